// Round 1
// baseline (2108.976 us; speedup 1.0000x reference)
//
#include <hip/hip_runtime.h>
#include <hip/hip_bf16.h>

#define NB 512
#define WD 256
#define NF 128

// ---------------- conv1d causal (dilated, pad 4, dil 2, K=3) ----------------
// Y[b][o][l] = conv_b[o] + sum_i sum_k W[o][i][k] * X[b][i][l-4+2k]  (zero pad)
// X viewed as [b][128][256] (reshape of X_time). Grid (4, NB): 2 o-tiles x 2 l-tiles.
__global__ __launch_bounds__(256) void conv_kernel(
    const float* __restrict__ X, const float* __restrict__ W,
    const float* __restrict__ bias, float* __restrict__ Y)
{
  __shared__ float Xs[16][132];
  __shared__ float Ws[64][49];   // 48 used, +1 pad (bank conflicts)
  int b = blockIdx.y;
  int o0 = (blockIdx.x >> 1) * 64;
  int l0 = (blockIdx.x & 1) * 128;
  int t = threadIdx.x, tx = t & 15, ty = t >> 4;
  const float* Xb = X + (size_t)b * (NF * WD);
  float acc[4][8] = {};
  for (int i0 = 0; i0 < NF; i0 += 16) {
    for (int idx = t; idx < 16 * 132; idx += 256) {
      int ii = idx / 132, c = idx - ii * 132;
      int l = l0 - 4 + c;
      Xs[ii][c] = (l >= 0) ? Xb[(i0 + ii) * WD + l] : 0.0f;
    }
    for (int idx = t; idx < 64 * 48; idx += 256) {
      int oo = idx / 48, j = idx - oo * 48;
      Ws[oo][j] = W[(size_t)(o0 + oo) * 384 + i0 * 3 + j];
    }
    __syncthreads();
#pragma unroll
    for (int ii = 0; ii < 16; ++ii) {
      float xr[12];
#pragma unroll
      for (int c = 0; c < 12; ++c) xr[c] = Xs[ii][tx * 8 + c];
#pragma unroll
      for (int oy = 0; oy < 4; ++oy) {
        float w0 = Ws[ty * 4 + oy][ii * 3 + 0];
        float w1 = Ws[ty * 4 + oy][ii * 3 + 1];
        float w2 = Ws[ty * 4 + oy][ii * 3 + 2];
#pragma unroll
        for (int j = 0; j < 8; ++j)
          acc[oy][j] += w0 * xr[j] + w1 * xr[j + 2] + w2 * xr[j + 4];
      }
    }
    __syncthreads();
  }
#pragma unroll
  for (int oy = 0; oy < 4; ++oy) {
    int o = o0 + ty * 4 + oy;
    float bv = bias[o];
    float* Yr = Y + (size_t)b * (NF * WD) + (size_t)o * WD + l0 + tx * 8;
#pragma unroll
    for (int j = 0; j < 8; ++j) Yr[j] = acc[oy][j] + bv;
  }
}

// ---------------- gram + row softmax, per batch; P[b][n][m] in bf16 ----------------
// S[n][m] = dq[n]*dk[m]*(X[b,n,:].X[b,m,:])*scale; P = softmax_m(S)
template <int N, int D>
__global__ __launch_bounds__(256) void gram_softmax(
    const float* __restrict__ X, const float* __restrict__ Wq,
    const float* __restrict__ Wk, __hip_bfloat16* __restrict__ P, float scale)
{
  __shared__ float S[64][N];
  __shared__ float XR[64][33];
  __shared__ float XM[64][33];
  __shared__ float dqs[64];
  __shared__ float dks[N];
  int b = blockIdx.y, n0 = blockIdx.x * 64;
  int t = threadIdx.x, tx = t & 15, ty = t >> 4;
  const float* Xb = X + (size_t)b * N * D;
  if (t < 64) dqs[t] = Wq[(size_t)(n0 + t) * (N + 1)];
  for (int c = t; c < N; c += 256) dks[c] = Wk[(size_t)c * (N + 1)];

  for (int m0 = 0; m0 < N; m0 += 64) {
    float acc[4][4] = {};
    for (int k0 = 0; k0 < D; k0 += 32) {
      int row = t >> 2, cs = (t & 3) * 8;
      const float* s1 = Xb + (size_t)(n0 + row) * D + k0 + cs;
      const float* s2 = Xb + (size_t)(m0 + row) * D + k0 + cs;
      float4 a0 = *(const float4*)s1;
      float4 a1 = *(const float4*)(s1 + 4);
      float4 b0 = *(const float4*)s2;
      float4 b1 = *(const float4*)(s2 + 4);
      XR[row][cs + 0] = a0.x; XR[row][cs + 1] = a0.y; XR[row][cs + 2] = a0.z; XR[row][cs + 3] = a0.w;
      XR[row][cs + 4] = a1.x; XR[row][cs + 5] = a1.y; XR[row][cs + 6] = a1.z; XR[row][cs + 7] = a1.w;
      XM[row][cs + 0] = b0.x; XM[row][cs + 1] = b0.y; XM[row][cs + 2] = b0.z; XM[row][cs + 3] = b0.w;
      XM[row][cs + 4] = b1.x; XM[row][cs + 5] = b1.y; XM[row][cs + 6] = b1.z; XM[row][cs + 7] = b1.w;
      __syncthreads();
#pragma unroll
      for (int kk = 0; kk < 32; ++kk) {
        float av[4], bv[4];
#pragma unroll
        for (int i = 0; i < 4; ++i) av[i] = XR[ty * 4 + i][kk];
#pragma unroll
        for (int j = 0; j < 4; ++j) bv[j] = XM[tx * 4 + j][kk];
#pragma unroll
        for (int i = 0; i < 4; ++i)
#pragma unroll
          for (int j = 0; j < 4; ++j) acc[i][j] += av[i] * bv[j];
      }
      __syncthreads();
    }
#pragma unroll
    for (int i = 0; i < 4; ++i)
#pragma unroll
      for (int j = 0; j < 4; ++j)
        S[ty * 4 + i][m0 + tx * 4 + j] =
            acc[i][j] * dqs[ty * 4 + i] * dks[m0 + tx * 4 + j] * scale;
  }
  __syncthreads();
  int wave = t >> 6, lane = t & 63;
  constexpr int NL = N / 64;
  for (int rr = 0; rr < 16; ++rr) {
    int r = wave * 16 + rr;
    float v[NL];
    float mx = -3.0e38f;
#pragma unroll
    for (int q = 0; q < NL; ++q) { v[q] = S[r][lane + 64 * q]; mx = fmaxf(mx, v[q]); }
#pragma unroll
    for (int off = 32; off > 0; off >>= 1) mx = fmaxf(mx, __shfl_xor(mx, off));
    float sum = 0.f;
#pragma unroll
    for (int q = 0; q < NL; ++q) { v[q] = __expf(v[q] - mx); sum += v[q]; }
#pragma unroll
    for (int off = 32; off > 0; off >>= 1) sum += __shfl_xor(sum, off);
    float inv = 1.0f / sum;
    __hip_bfloat16* Pr = P + (size_t)b * N * N + (size_t)(n0 + r) * N + lane;
#pragma unroll
    for (int q = 0; q < NL; ++q) Pr[64 * q] = __float2bfloat16(v[q] * inv);
  }
}

// A[n][m] = mean_b P[b][n][m]; write to ws copy and to d_out
__global__ void reduceA(const __hip_bfloat16* __restrict__ P, float* __restrict__ A1,
                        float* __restrict__ A2, int N)
{
  int idx = blockIdx.x * 256 + threadIdx.x;
  size_t st = (size_t)N * N;
  const __hip_bfloat16* p = P + idx;
  float s = 0.f;
  for (int b = 0; b < NB; ++b) s += __bfloat162float(p[(size_t)b * st]);
  s *= (1.0f / NB);
  A1[idx] = s;
  A2[idx] = s;
}

__global__ void deg_dis(const float* __restrict__ A, float* __restrict__ dis, int N)
{
  int c = threadIdx.x;
  if (c < N) {
    float d = 0.f;
    for (int r = 0; r < N; ++r) d += A[r * N + c];
    dis[c] = (d > 0.f) ? (1.0f / sqrtf(d)) : 0.0f;
  }
}

// MT[c][r] = dis[c]*dis[r]*A[r][c]
__global__ void mt_kernel(const float* __restrict__ A, const float* __restrict__ dis,
                          float* __restrict__ MT, int N)
{
  int idx = blockIdx.x * 256 + threadIdx.x;
  int c = idx / N, r = idx - c * N;
  MT[idx] = dis[c] * dis[r] * A[r * N + c];
}

// ---------------- generic batched GEMM: C[b][N][128] = A[b][N][K] * B[b][K][128] (+bias) ----
// strides sA/sB/sC select batched vs shared operands (stride 0 = shared).
__global__ __launch_bounds__(256) void gemm_bk(
    const float* __restrict__ A, long sA, const float* __restrict__ Bm, long sB,
    const float* __restrict__ bias, float* __restrict__ C, long sC, int N, int Kdim)
{
  __shared__ float As[64][33];
  __shared__ float Bs[32][128];
  int b = blockIdx.y, n0 = blockIdx.x * 64;
  int t = threadIdx.x, tx = t & 15, ty = t >> 4;
  const float* Ab = A + (size_t)b * sA;
  const float* Bb = Bm + (size_t)b * sB;
  float acc[4][8] = {};
  for (int k0 = 0; k0 < Kdim; k0 += 32) {
    {
      int row = t >> 2, cs = (t & 3) * 8;
      const float* src = Ab + (size_t)(n0 + row) * Kdim + k0 + cs;
      float4 v0 = *(const float4*)src;
      float4 v1 = *(const float4*)(src + 4);
      As[row][cs + 0] = v0.x; As[row][cs + 1] = v0.y; As[row][cs + 2] = v0.z; As[row][cs + 3] = v0.w;
      As[row][cs + 4] = v1.x; As[row][cs + 5] = v1.y; As[row][cs + 6] = v1.z; As[row][cs + 7] = v1.w;
    }
    {
      int row = t >> 3, cs = (t & 7) * 16;
      const float* src = Bb + (size_t)(k0 + row) * 128 + cs;
      float4 v0 = *(const float4*)src;
      float4 v1 = *(const float4*)(src + 4);
      float4 v2 = *(const float4*)(src + 8);
      float4 v3 = *(const float4*)(src + 12);
      *(float4*)&Bs[row][cs] = v0;
      *(float4*)&Bs[row][cs + 4] = v1;
      *(float4*)&Bs[row][cs + 8] = v2;
      *(float4*)&Bs[row][cs + 12] = v3;
    }
    __syncthreads();
#pragma unroll
    for (int kk = 0; kk < 32; ++kk) {
      float av[4], bv[8];
#pragma unroll
      for (int i = 0; i < 4; ++i) av[i] = As[ty * 4 + i][kk];
#pragma unroll
      for (int j = 0; j < 4; ++j) bv[j] = Bs[kk][tx * 4 + j];
#pragma unroll
      for (int j = 0; j < 4; ++j) bv[4 + j] = Bs[kk][64 + tx * 4 + j];
#pragma unroll
      for (int i = 0; i < 4; ++i)
#pragma unroll
        for (int j = 0; j < 8; ++j) acc[i][j] += av[i] * bv[j];
    }
    __syncthreads();
  }
  float* Cb = C + (size_t)b * sC;
#pragma unroll
  for (int i = 0; i < 4; ++i) {
    int n = n0 + ty * 4 + i;
    float* Cr = Cb + (size_t)n * 128;
    float o0[4], o1[4];
#pragma unroll
    for (int j = 0; j < 4; ++j) {
      float b0 = bias ? bias[tx * 4 + j] : 0.0f;
      float b1 = bias ? bias[64 + tx * 4 + j] : 0.0f;
      o0[j] = acc[i][j] + b0;
      o1[j] = acc[i][4 + j] + b1;
    }
    *(float4*)(Cr + tx * 4) = make_float4(o0[0], o0[1], o0[2], o0[3]);
    *(float4*)(Cr + 64 + tx * 4) = make_float4(o1[0], o1[1], o1[2], o1[3]);
  }
}

// out[b][h] = mean_c H[b][c][h]
__global__ void mean_nodes(const float* __restrict__ Hb, float* __restrict__ out, int N)
{
  int b = blockIdx.x, h = threadIdx.x;  // 128 threads
  const float* p = Hb + (size_t)b * N * 128 + h;
  float s = 0.f;
  for (int c = 0; c < N; ++c) s += p[c * 128];
  out[b * 128 + h] = s * (1.0f / N);
}

__global__ void proj_kernel(const float* __restrict__ of, const float* __restrict__ ot,
                            const float* __restrict__ pw, const float* __restrict__ pb,
                            float* __restrict__ out)
{
  int idx = blockIdx.x * 256 + threadIdx.x;  // < 512*64
  int b = idx >> 6, o = idx & 63;
  float s = pb[o];
  const float* f = of + b * 128;
  const float* tt = ot + b * 128;
#pragma unroll 4
  for (int j = 0; j < 128; ++j) s += f[j] * pw[j * 64 + o];
#pragma unroll 4
  for (int j = 0; j < 128; ++j) s += tt[j] * pw[(128 + j) * 64 + o];
  out[idx] = s;
}

extern "C" void kernel_launch(void* const* d_in, const int* in_sizes, int n_in,
                              void* d_out, int out_size, void* d_ws, size_t ws_size,
                              hipStream_t stream)
{
  const float* X_time = (const float*)d_in[0];
  const float* conv_w = (const float*)d_in[1];
  const float* conv_b = (const float*)d_in[2];
  const float* wq_feat = (const float*)d_in[3];
  const float* wk_feat = (const float*)d_in[4];
  const float* wq_time = (const float*)d_in[5];
  const float* wk_time = (const float*)d_in[6];
  const float* gf1_w = (const float*)d_in[7];
  const float* gf1_b = (const float*)d_in[8];
  const float* gf2_w = (const float*)d_in[9];
  const float* gf2_b = (const float*)d_in[10];
  const float* gf3_w = (const float*)d_in[11];
  const float* gf3_b = (const float*)d_in[12];
  const float* gt1_w = (const float*)d_in[13];
  const float* gt1_b = (const float*)d_in[14];
  const float* gt2_w = (const float*)d_in[15];
  const float* gt2_b = (const float*)d_in[16];
  const float* gt3_w = (const float*)d_in[17];
  const float* gt3_b = (const float*)d_in[18];
  const float* proj_w = (const float*)d_in[19];
  const float* proj_b = (const float*)d_in[20];

  char* ws = (char*)d_ws;
  const size_t MB64 = 64ull << 20;
  float* R0 = (float*)ws;              // XF -> feat h2 -> time T ping-pong
  float* R1 = (float*)(ws + MB64);     // P_feat -> feat T -> time h ping-pong
  float* R2 = (float*)(ws + 2 * MB64); // P_time -> feat h
  float* SM = (float*)(ws + 3 * MB64);
  float* A_feat = SM;                  // 16384
  float* A_time = SM + 16384;          // 65536
  float* MT_feat = SM + 81920;         // 16384
  float* MT_time = SM + 98304;         // 65536
  float* dis_f = SM + 163840;          // 128
  float* dis_t = SM + 164096;          // 256
  float* out_f = SM + 164608;          // 65536
  float* out_t = SM + 230144;          // 65536
  float* out = (float*)d_out;
  float* outA_f = out + 32768;
  float* outA_t = out + 49152;
  __hip_bfloat16* Pf = (__hip_bfloat16*)R1;
  __hip_bfloat16* Pt = (__hip_bfloat16*)R2;

  // 1) conv: X_time (reshaped [b][128][256]) -> XF in R0
  conv_kernel<<<dim3(4, NB), 256, 0, stream>>>(X_time, conv_w, conv_b, R0);
  // 2) grams + per-batch softmax (bf16 staging)
  gram_softmax<128, 256><<<dim3(2, NB), 256, 0, stream>>>(R0, wq_feat, wk_feat, Pf, 0.0625f);
  gram_softmax<256, 128><<<dim3(4, NB), 256, 0, stream>>>(X_time, wq_time, wk_time, Pt,
                                                          0.08838834764831845f);
  // 3) batch mean -> A (ws + d_out)
  reduceA<<<64, 256, 0, stream>>>(Pf, A_feat, outA_f, 128);
  reduceA<<<256, 256, 0, stream>>>(Pt, A_time, outA_t, 256);
  // 4) normalized adjacency, transposed: MT[c][r] = dis[c]dis[r]A[r][c]
  deg_dis<<<1, 128, 0, stream>>>(A_feat, dis_f, 128);
  deg_dis<<<1, 256, 0, stream>>>(A_time, dis_t, 256);
  mt_kernel<<<64, 256, 0, stream>>>(A_feat, dis_f, MT_feat, 128);
  mt_kernel<<<256, 256, 0, stream>>>(A_time, dis_t, MT_time, 256);

  // 5) feat GCN: N=128; T in R1, h in R2/R0
  gemm_bk<<<dim3(2, NB), 256, 0, stream>>>(R0, 32768, gf1_w, 0, nullptr, R1, 16384, 128, 256);
  gemm_bk<<<dim3(2, NB), 256, 0, stream>>>(MT_feat, 0, R1, 16384, gf1_b, R2, 16384, 128, 128);
  gemm_bk<<<dim3(2, NB), 256, 0, stream>>>(R2, 16384, gf2_w, 0, nullptr, R1, 16384, 128, 128);
  gemm_bk<<<dim3(2, NB), 256, 0, stream>>>(MT_feat, 0, R1, 16384, gf2_b, R0, 16384, 128, 128);
  gemm_bk<<<dim3(2, NB), 256, 0, stream>>>(R0, 16384, gf3_w, 0, nullptr, R1, 16384, 128, 128);
  gemm_bk<<<dim3(2, NB), 256, 0, stream>>>(MT_feat, 0, R1, 16384, gf3_b, R2, 16384, 128, 128);
  mean_nodes<<<NB, 128, 0, stream>>>(R2, out_f, 128);

  // 6) time GCN: N=256; ping-pong R0 (T) / R1 (h)
  gemm_bk<<<dim3(4, NB), 256, 0, stream>>>(X_time, 32768, gt1_w, 0, nullptr, R0, 32768, 256, 128);
  gemm_bk<<<dim3(4, NB), 256, 0, stream>>>(MT_time, 0, R0, 32768, gt1_b, R1, 32768, 256, 256);
  gemm_bk<<<dim3(4, NB), 256, 0, stream>>>(R1, 32768, gt2_w, 0, nullptr, R0, 32768, 256, 128);
  gemm_bk<<<dim3(4, NB), 256, 0, stream>>>(MT_time, 0, R0, 32768, gt2_b, R1, 32768, 256, 256);
  gemm_bk<<<dim3(4, NB), 256, 0, stream>>>(R1, 32768, gt3_w, 0, nullptr, R0, 32768, 256, 128);
  gemm_bk<<<dim3(4, NB), 256, 0, stream>>>(MT_time, 0, R0, 32768, gt3_b, R1, 32768, 256, 256);
  mean_nodes<<<NB, 128, 0, stream>>>(R1, out_t, 256);

  // 7) projection
  proj_kernel<<<128, 256, 0, stream>>>(out_f, out_t, proj_w, proj_b, out);
}

// Round 2
// 1951.631 us; speedup vs baseline: 1.0806x; 1.0806x over previous
//
#include <hip/hip_runtime.h>
#include <hip/hip_bf16.h>

#define NB 512
#define WD 256
#define NF 128

// ---------------- conv1d causal (dilated, pad 4, dil 2, K=3) ----------------
// Y[b][o][l] = conv_b[o] + sum_i sum_k W[o][i][k] * X[b][i][l-4+2k]  (zero pad)
// Block: 64 o-rows x full 256 l. Per-thread 4 o x 16 l. Grid (2, NB).
__global__ __launch_bounds__(256) void conv_kernel(
    const float* __restrict__ X, const float* __restrict__ W,
    const float* __restrict__ bias, float* __restrict__ Y)
{
  __shared__ float Xs[16][264];   // cols 0..3 = zero halo (l=-4..-1), 4+l for l in 0..255
  __shared__ float Ws2[48][66];   // [local_i*3+k][o], 2-way-free reads
  int b = blockIdx.y;
  int o0 = blockIdx.x * 64;
  int t = threadIdx.x, tx = t & 15, ty = t >> 4;
  const float* Xb = X + (size_t)b * (NF * WD);
  float acc[4][16] = {};
  if (t < 16) *(float4*)&Xs[t][0] = make_float4(0.f, 0.f, 0.f, 0.f);  // halo, never overwritten
  for (int i0 = 0; i0 < NF; i0 += 16) {
    // stage X: 4 aligned float4 per thread
    {
      const float* src = Xb + (size_t)(i0 + ty) * WD;
#pragma unroll
      for (int j = 0; j < 4; ++j) {
        int col4 = tx + 16 * j;
        *(float4*)&Xs[ty][4 + col4 * 4] = *(const float4*)(src + col4 * 4);
      }
    }
    // stage W transposed: 3 float4 loads + 12 scalar scatter writes
    {
      int o = t >> 2, q = t & 3;
      const float* wsrc = W + (size_t)(o0 + o) * 384 + i0 * 3;
#pragma unroll
      for (int m = 0; m < 3; ++m) {
        int c4 = q + 4 * m;
        float4 w = *(const float4*)(wsrc + c4 * 4);
        Ws2[c4 * 4 + 0][o] = w.x;
        Ws2[c4 * 4 + 1][o] = w.y;
        Ws2[c4 * 4 + 2][o] = w.z;
        Ws2[c4 * 4 + 3][o] = w.w;
      }
    }
    __syncthreads();
#pragma unroll
    for (int ii = 0; ii < 16; ++ii) {
      float w0[4], w1[4], w2[4];
#pragma unroll
      for (int oy = 0; oy < 4; ++oy) {
        w0[oy] = Ws2[ii * 3 + 0][ty * 4 + oy];
        w1[oy] = Ws2[ii * 3 + 1][ty * 4 + oy];
        w2[oy] = Ws2[ii * 3 + 2][ty * 4 + oy];
      }
#pragma unroll
      for (int g = 0; g < 4; ++g) {
        float x[8];
        *(float4*)&x[0] = *(const float4*)&Xs[ii][g * 64 + tx * 4];
        *(float4*)&x[4] = *(const float4*)&Xs[ii][g * 64 + tx * 4 + 4];
#pragma unroll
        for (int oy = 0; oy < 4; ++oy)
#pragma unroll
          for (int j = 0; j < 4; ++j)
            acc[oy][g * 4 + j] += w0[oy] * x[j] + w1[oy] * x[j + 2] + w2[oy] * x[j + 4];
      }
    }
    __syncthreads();
  }
#pragma unroll
  for (int oy = 0; oy < 4; ++oy) {
    int o = o0 + ty * 4 + oy;
    float bv = bias[o];
    float* Yr = Y + (size_t)b * (NF * WD) + (size_t)o * WD;
#pragma unroll
    for (int g = 0; g < 4; ++g) {
      float4 v = make_float4(acc[oy][g * 4 + 0] + bv, acc[oy][g * 4 + 1] + bv,
                             acc[oy][g * 4 + 2] + bv, acc[oy][g * 4 + 3] + bv);
      *(float4*)(Yr + g * 64 + tx * 4) = v;
    }
  }
}

// ---------------- gram + row softmax, per batch; P[b][n][m] in bf16 ----------------
// Scores kept fully in registers; softmax via 16-lane shfl subgroup reduce.
__device__ inline unsigned pk2bf(float a, float b) {
  __hip_bfloat162 h;
  h.x = __float2bfloat16(a);
  h.y = __float2bfloat16(b);
  unsigned r;
  __builtin_memcpy(&r, &h, 4);
  return r;
}

template <int N, int D>
__global__ __launch_bounds__(256) void gram_softmax(
    const float* __restrict__ X, const float* __restrict__ Wq,
    const float* __restrict__ Wk, __hip_bfloat16* __restrict__ P, float scale)
{
  __shared__ float XR[64][33];
  __shared__ float XM[64][33];
  __shared__ float dqs[64];
  __shared__ float dks[N];
  int b = blockIdx.y, n0 = blockIdx.x * 64;
  int t = threadIdx.x, tx = t & 15, ty = t >> 4;
  const float* Xb = X + (size_t)b * N * D;
  if (t < 64) dqs[t] = Wq[(size_t)(n0 + t) * (N + 1)];
  for (int c = t; c < N; c += 256) dks[c] = Wk[(size_t)c * (N + 1)];
  __syncthreads();

  constexpr int NT = N / 64;
  float s[4][4 * NT];
  for (int mt = 0; mt < NT; ++mt) {
    int m0 = mt * 64;
    float acc[4][4] = {};
    for (int k0 = 0; k0 < D; k0 += 32) {
      int row = t >> 2, cs = (t & 3) * 8;
      const float* s1 = Xb + (size_t)(n0 + row) * D + k0 + cs;
      const float* s2 = Xb + (size_t)(m0 + row) * D + k0 + cs;
      float4 a0 = *(const float4*)s1;
      float4 a1 = *(const float4*)(s1 + 4);
      float4 b0 = *(const float4*)s2;
      float4 b1 = *(const float4*)(s2 + 4);
      XR[row][cs + 0] = a0.x; XR[row][cs + 1] = a0.y; XR[row][cs + 2] = a0.z; XR[row][cs + 3] = a0.w;
      XR[row][cs + 4] = a1.x; XR[row][cs + 5] = a1.y; XR[row][cs + 6] = a1.z; XR[row][cs + 7] = a1.w;
      XM[row][cs + 0] = b0.x; XM[row][cs + 1] = b0.y; XM[row][cs + 2] = b0.z; XM[row][cs + 3] = b0.w;
      XM[row][cs + 4] = b1.x; XM[row][cs + 5] = b1.y; XM[row][cs + 6] = b1.z; XM[row][cs + 7] = b1.w;
      __syncthreads();
#pragma unroll
      for (int kk = 0; kk < 32; ++kk) {
        float av[4], bv[4];
#pragma unroll
        for (int i = 0; i < 4; ++i) av[i] = XR[ty * 4 + i][kk];
#pragma unroll
        for (int j = 0; j < 4; ++j) bv[j] = XM[tx * 4 + j][kk];
#pragma unroll
        for (int i = 0; i < 4; ++i)
#pragma unroll
          for (int j = 0; j < 4; ++j) acc[i][j] += av[i] * bv[j];
      }
      __syncthreads();
    }
#pragma unroll
    for (int i = 0; i < 4; ++i)
#pragma unroll
      for (int j = 0; j < 4; ++j)
        s[i][mt * 4 + j] = acc[i][j] * dqs[ty * 4 + i] * dks[m0 + tx * 4 + j] * scale;
  }

  // in-register row softmax: row (n0+ty*4+i) lives across the 16 tx lanes of this ty group
#pragma unroll
  for (int i = 0; i < 4; ++i) {
    float mx = s[i][0];
#pragma unroll
    for (int q = 1; q < 4 * NT; ++q) mx = fmaxf(mx, s[i][q]);
#pragma unroll
    for (int off = 1; off < 16; off <<= 1) mx = fmaxf(mx, __shfl_xor(mx, off));
    float sum = 0.f;
#pragma unroll
    for (int q = 0; q < 4 * NT; ++q) { s[i][q] = __expf(s[i][q] - mx); sum += s[i][q]; }
#pragma unroll
    for (int off = 1; off < 16; off <<= 1) sum += __shfl_xor(sum, off);
    float inv = 1.0f / sum;
    __hip_bfloat16* Pr = P + (size_t)b * N * N + (size_t)(n0 + ty * 4 + i) * N;
#pragma unroll
    for (int mt = 0; mt < NT; ++mt) {
      uint2 pk;
      pk.x = pk2bf(s[i][mt * 4 + 0] * inv, s[i][mt * 4 + 1] * inv);
      pk.y = pk2bf(s[i][mt * 4 + 2] * inv, s[i][mt * 4 + 3] * inv);
      *(uint2*)(Pr + mt * 64 + tx * 4) = pk;
    }
  }
}

// A[n][m] = mean_b P[b][n][m]; write to ws copy and to d_out
__global__ void reduceA(const __hip_bfloat16* __restrict__ P, float* __restrict__ A1,
                        float* __restrict__ A2, int N)
{
  int idx = blockIdx.x * 256 + threadIdx.x;
  size_t st = (size_t)N * N;
  const __hip_bfloat16* p = P + idx;
  float s = 0.f;
  for (int b = 0; b < NB; ++b) s += __bfloat162float(p[(size_t)b * st]);
  s *= (1.0f / NB);
  A1[idx] = s;
  A2[idx] = s;
}

__global__ void deg_dis(const float* __restrict__ A, float* __restrict__ dis, int N)
{
  int c = threadIdx.x;
  if (c < N) {
    float d = 0.f;
    for (int r = 0; r < N; ++r) d += A[r * N + c];
    dis[c] = (d > 0.f) ? (1.0f / sqrtf(d)) : 0.0f;
  }
}

// MT[c][r] = dis[c]*dis[r]*A[r][c]
__global__ void mt_kernel(const float* __restrict__ A, const float* __restrict__ dis,
                          float* __restrict__ MT, int N)
{
  int idx = blockIdx.x * 256 + threadIdx.x;
  int c = idx / N, r = idx - c * N;
  MT[idx] = dis[c] * dis[r] * A[r * N + c];
}

// ---------------- generic batched GEMM: C[b][N][128] = A[b][N][K] * B[b][K][128] (+bias) ----
__global__ __launch_bounds__(256) void gemm_bk(
    const float* __restrict__ A, long sA, const float* __restrict__ Bm, long sB,
    const float* __restrict__ bias, float* __restrict__ C, long sC, int N, int Kdim)
{
  __shared__ float As[64][33];
  __shared__ float Bs[32][128];
  int b = blockIdx.y, n0 = blockIdx.x * 64;
  int t = threadIdx.x, tx = t & 15, ty = t >> 4;
  const float* Ab = A + (size_t)b * sA;
  const float* Bb = Bm + (size_t)b * sB;
  float acc[4][8] = {};
  for (int k0 = 0; k0 < Kdim; k0 += 32) {
    {
      int row = t >> 2, cs = (t & 3) * 8;
      const float* src = Ab + (size_t)(n0 + row) * Kdim + k0 + cs;
      float4 v0 = *(const float4*)src;
      float4 v1 = *(const float4*)(src + 4);
      As[row][cs + 0] = v0.x; As[row][cs + 1] = v0.y; As[row][cs + 2] = v0.z; As[row][cs + 3] = v0.w;
      As[row][cs + 4] = v1.x; As[row][cs + 5] = v1.y; As[row][cs + 6] = v1.z; As[row][cs + 7] = v1.w;
    }
    {
      int row = t >> 3, cs = (t & 7) * 16;
      const float* src = Bb + (size_t)(k0 + row) * 128 + cs;
      float4 v0 = *(const float4*)src;
      float4 v1 = *(const float4*)(src + 4);
      float4 v2 = *(const float4*)(src + 8);
      float4 v3 = *(const float4*)(src + 12);
      *(float4*)&Bs[row][cs] = v0;
      *(float4*)&Bs[row][cs + 4] = v1;
      *(float4*)&Bs[row][cs + 8] = v2;
      *(float4*)&Bs[row][cs + 12] = v3;
    }
    __syncthreads();
#pragma unroll
    for (int kk = 0; kk < 32; ++kk) {
      float av[4], bv[8];
#pragma unroll
      for (int i = 0; i < 4; ++i) av[i] = As[ty * 4 + i][kk];
#pragma unroll
      for (int j = 0; j < 4; ++j) bv[j] = Bs[kk][tx * 4 + j];
#pragma unroll
      for (int j = 0; j < 4; ++j) bv[4 + j] = Bs[kk][64 + tx * 4 + j];
#pragma unroll
      for (int i = 0; i < 4; ++i)
#pragma unroll
        for (int j = 0; j < 8; ++j) acc[i][j] += av[i] * bv[j];
    }
    __syncthreads();
  }
  float* Cb = C + (size_t)b * sC;
#pragma unroll
  for (int i = 0; i < 4; ++i) {
    int n = n0 + ty * 4 + i;
    float* Cr = Cb + (size_t)n * 128;
    float o0[4], o1[4];
#pragma unroll
    for (int j = 0; j < 4; ++j) {
      float b0 = bias ? bias[tx * 4 + j] : 0.0f;
      float b1 = bias ? bias[64 + tx * 4 + j] : 0.0f;
      o0[j] = acc[i][j] + b0;
      o1[j] = acc[i][4 + j] + b1;
    }
    *(float4*)(Cr + tx * 4) = make_float4(o0[0], o0[1], o0[2], o0[3]);
    *(float4*)(Cr + 64 + tx * 4) = make_float4(o1[0], o1[1], o1[2], o1[3]);
  }
}

// out[b][h] = mean_c H[b][c][h]
__global__ void mean_nodes(const float* __restrict__ Hb, float* __restrict__ out, int N)
{
  int b = blockIdx.x, h = threadIdx.x;  // 128 threads
  const float* p = Hb + (size_t)b * N * 128 + h;
  float s = 0.f;
  for (int c = 0; c < N; ++c) s += p[c * 128];
  out[b * 128 + h] = s * (1.0f / N);
}

__global__ void proj_kernel(const float* __restrict__ of, const float* __restrict__ ot,
                            const float* __restrict__ pw, const float* __restrict__ pb,
                            float* __restrict__ out)
{
  int idx = blockIdx.x * 256 + threadIdx.x;  // < 512*64
  int b = idx >> 6, o = idx & 63;
  float s = pb[o];
  const float* f = of + b * 128;
  const float* tt = ot + b * 128;
#pragma unroll 4
  for (int j = 0; j < 128; ++j) s += f[j] * pw[j * 64 + o];
#pragma unroll 4
  for (int j = 0; j < 128; ++j) s += tt[j] * pw[(128 + j) * 64 + o];
  out[idx] = s;
}

extern "C" void kernel_launch(void* const* d_in, const int* in_sizes, int n_in,
                              void* d_out, int out_size, void* d_ws, size_t ws_size,
                              hipStream_t stream)
{
  const float* X_time = (const float*)d_in[0];
  const float* conv_w = (const float*)d_in[1];
  const float* conv_b = (const float*)d_in[2];
  const float* wq_feat = (const float*)d_in[3];
  const float* wk_feat = (const float*)d_in[4];
  const float* wq_time = (const float*)d_in[5];
  const float* wk_time = (const float*)d_in[6];
  const float* gf1_w = (const float*)d_in[7];
  const float* gf1_b = (const float*)d_in[8];
  const float* gf2_w = (const float*)d_in[9];
  const float* gf2_b = (const float*)d_in[10];
  const float* gf3_w = (const float*)d_in[11];
  const float* gf3_b = (const float*)d_in[12];
  const float* gt1_w = (const float*)d_in[13];
  const float* gt1_b = (const float*)d_in[14];
  const float* gt2_w = (const float*)d_in[15];
  const float* gt2_b = (const float*)d_in[16];
  const float* gt3_w = (const float*)d_in[17];
  const float* gt3_b = (const float*)d_in[18];
  const float* proj_w = (const float*)d_in[19];
  const float* proj_b = (const float*)d_in[20];

  char* ws = (char*)d_ws;
  const size_t MB64 = 64ull << 20;
  float* R0 = (float*)ws;              // XF -> feat h2 -> time T ping-pong
  float* R1 = (float*)(ws + MB64);     // P_feat -> feat T -> time h ping-pong
  float* R2 = (float*)(ws + 2 * MB64); // P_time -> feat h
  float* SM = (float*)(ws + 3 * MB64);
  float* A_feat = SM;                  // 16384
  float* A_time = SM + 16384;          // 65536
  float* MT_feat = SM + 81920;         // 16384
  float* MT_time = SM + 98304;         // 65536
  float* dis_f = SM + 163840;          // 128
  float* dis_t = SM + 164096;          // 256
  float* out_f = SM + 164608;          // 65536
  float* out_t = SM + 230144;          // 65536
  float* out = (float*)d_out;
  float* outA_f = out + 32768;
  float* outA_t = out + 49152;
  __hip_bfloat16* Pf = (__hip_bfloat16*)R1;
  __hip_bfloat16* Pt = (__hip_bfloat16*)R2;

  // 1) conv: X_time (reshaped [b][128][256]) -> XF in R0
  conv_kernel<<<dim3(2, NB), 256, 0, stream>>>(X_time, conv_w, conv_b, R0);
  // 2) grams + per-batch softmax (bf16 staging)
  gram_softmax<128, 256><<<dim3(2, NB), 256, 0, stream>>>(R0, wq_feat, wk_feat, Pf, 0.0625f);
  gram_softmax<256, 128><<<dim3(4, NB), 256, 0, stream>>>(X_time, wq_time, wk_time, Pt,
                                                          0.08838834764831845f);
  // 3) batch mean -> A (ws + d_out)
  reduceA<<<64, 256, 0, stream>>>(Pf, A_feat, outA_f, 128);
  reduceA<<<256, 256, 0, stream>>>(Pt, A_time, outA_t, 256);
  // 4) normalized adjacency, transposed: MT[c][r] = dis[c]dis[r]A[r][c]
  deg_dis<<<1, 128, 0, stream>>>(A_feat, dis_f, 128);
  deg_dis<<<1, 256, 0, stream>>>(A_time, dis_t, 256);
  mt_kernel<<<64, 256, 0, stream>>>(A_feat, dis_f, MT_feat, 128);
  mt_kernel<<<256, 256, 0, stream>>>(A_time, dis_t, MT_time, 256);

  // 5) feat GCN: N=128; T in R1, h in R2/R0
  gemm_bk<<<dim3(2, NB), 256, 0, stream>>>(R0, 32768, gf1_w, 0, nullptr, R1, 16384, 128, 256);
  gemm_bk<<<dim3(2, NB), 256, 0, stream>>>(MT_feat, 0, R1, 16384, gf1_b, R2, 16384, 128, 128);
  gemm_bk<<<dim3(2, NB), 256, 0, stream>>>(R2, 16384, gf2_w, 0, nullptr, R1, 16384, 128, 128);
  gemm_bk<<<dim3(2, NB), 256, 0, stream>>>(MT_feat, 0, R1, 16384, gf2_b, R0, 16384, 128, 128);
  gemm_bk<<<dim3(2, NB), 256, 0, stream>>>(R0, 16384, gf3_w, 0, nullptr, R1, 16384, 128, 128);
  gemm_bk<<<dim3(2, NB), 256, 0, stream>>>(MT_feat, 0, R1, 16384, gf3_b, R2, 16384, 128, 128);
  mean_nodes<<<NB, 128, 0, stream>>>(R2, out_f, 128);

  // 6) time GCN: N=256; ping-pong R0 (T) / R1 (h)
  gemm_bk<<<dim3(4, NB), 256, 0, stream>>>(X_time, 32768, gt1_w, 0, nullptr, R0, 32768, 256, 128);
  gemm_bk<<<dim3(4, NB), 256, 0, stream>>>(MT_time, 0, R0, 32768, gt1_b, R1, 32768, 256, 256);
  gemm_bk<<<dim3(4, NB), 256, 0, stream>>>(R1, 32768, gt2_w, 0, nullptr, R0, 32768, 256, 128);
  gemm_bk<<<dim3(4, NB), 256, 0, stream>>>(MT_time, 0, R0, 32768, gt2_b, R1, 32768, 256, 256);
  gemm_bk<<<dim3(4, NB), 256, 0, stream>>>(R1, 32768, gt3_w, 0, nullptr, R0, 32768, 256, 128);
  gemm_bk<<<dim3(4, NB), 256, 0, stream>>>(MT_time, 0, R0, 32768, gt3_b, R1, 32768, 256, 256);
  mean_nodes<<<NB, 128, 0, stream>>>(R1, out_t, 256);

  // 7) projection
  proj_kernel<<<128, 256, 0, stream>>>(out_f, out_t, proj_w, proj_b, out);
}

// Round 3
// 1111.915 us; speedup vs baseline: 1.8967x; 1.7552x over previous
//
#include <hip/hip_runtime.h>
#include <hip/hip_bf16.h>

#define NB 512
#define WD 256
#define NF 128

typedef __attribute__((ext_vector_type(8))) short short8v;
typedef __attribute__((ext_vector_type(4))) float f32x4;

__device__ inline unsigned pk2bf(float a, float b) {
  __hip_bfloat162 h;
  h.x = __float2bfloat16(a);
  h.y = __float2bfloat16(b);
  unsigned r;
  __builtin_memcpy(&r, &h, 4);
  return r;
}

// ---------------- conv1d causal (dilated, pad 4, dil 2, K=3) ----------------
// Y[b][o][l] = conv_b[o] + sum_i sum_k W[o][i][k] * X[b][i][l-4+2k]  (zero pad)
// Writes f32 (for gram) and bf16 row-major (for MFMA GEMM A-operand).
__global__ __launch_bounds__(256) void conv_kernel(
    const float* __restrict__ X, const float* __restrict__ W,
    const float* __restrict__ bias, float* __restrict__ Y,
    __hip_bfloat16* __restrict__ Yb)
{
  __shared__ float Xs[16][264];   // cols 0..3 = zero halo
  __shared__ float Ws2[48][66];   // [local_i*3+k][o]
  int b = blockIdx.y;
  int o0 = blockIdx.x * 64;
  int t = threadIdx.x, tx = t & 15, ty = t >> 4;
  const float* Xb = X + (size_t)b * (NF * WD);
  float acc[4][16] = {};
  if (t < 16) *(float4*)&Xs[t][0] = make_float4(0.f, 0.f, 0.f, 0.f);
  for (int i0 = 0; i0 < NF; i0 += 16) {
    {
      const float* src = Xb + (size_t)(i0 + ty) * WD;
#pragma unroll
      for (int j = 0; j < 4; ++j) {
        int col4 = tx + 16 * j;
        *(float4*)&Xs[ty][4 + col4 * 4] = *(const float4*)(src + col4 * 4);
      }
    }
    {
      int o = t >> 2, q = t & 3;
      const float* wsrc = W + (size_t)(o0 + o) * 384 + i0 * 3;
#pragma unroll
      for (int m = 0; m < 3; ++m) {
        int c4 = q + 4 * m;
        float4 w = *(const float4*)(wsrc + c4 * 4);
        Ws2[c4 * 4 + 0][o] = w.x;
        Ws2[c4 * 4 + 1][o] = w.y;
        Ws2[c4 * 4 + 2][o] = w.z;
        Ws2[c4 * 4 + 3][o] = w.w;
      }
    }
    __syncthreads();
#pragma unroll 2   // NOT full unroll: full unroll hoisted ~190 LDS values -> 256 VGPR + scratch spill (R2: 711MB spill writes)
    for (int ii = 0; ii < 16; ++ii) {
      float w0[4], w1[4], w2[4];
#pragma unroll
      for (int oy = 0; oy < 4; ++oy) {
        w0[oy] = Ws2[ii * 3 + 0][ty * 4 + oy];
        w1[oy] = Ws2[ii * 3 + 1][ty * 4 + oy];
        w2[oy] = Ws2[ii * 3 + 2][ty * 4 + oy];
      }
#pragma unroll
      for (int g = 0; g < 4; ++g) {
        float x[8];
        *(float4*)&x[0] = *(const float4*)&Xs[ii][g * 64 + tx * 4];
        *(float4*)&x[4] = *(const float4*)&Xs[ii][g * 64 + tx * 4 + 4];
#pragma unroll
        for (int oy = 0; oy < 4; ++oy)
#pragma unroll
          for (int j = 0; j < 4; ++j)
            acc[oy][g * 4 + j] += w0[oy] * x[j] + w1[oy] * x[j + 2] + w2[oy] * x[j + 4];
      }
    }
    __syncthreads();
  }
#pragma unroll
  for (int oy = 0; oy < 4; ++oy) {
    int o = o0 + ty * 4 + oy;
    float bv = bias[o];
    float* Yr = Y + (size_t)b * (NF * WD) + (size_t)o * WD;
    __hip_bfloat16* Yr2 = Yb + (size_t)b * (NF * WD) + (size_t)o * WD;
#pragma unroll
    for (int g = 0; g < 4; ++g) {
      float v0 = acc[oy][g * 4 + 0] + bv, v1 = acc[oy][g * 4 + 1] + bv;
      float v2 = acc[oy][g * 4 + 2] + bv, v3 = acc[oy][g * 4 + 3] + bv;
      *(float4*)(Yr + g * 64 + tx * 4) = make_float4(v0, v1, v2, v3);
      uint2 p;
      p.x = pk2bf(v0, v1);
      p.y = pk2bf(v2, v3);
      *(uint2*)(Yr2 + g * 64 + tx * 4) = p;
    }
  }
}

// ---------------- gram + row softmax, per batch; P[b][n][m] in bf16 (f32 compute) ----
template <int N, int D>
__global__ __launch_bounds__(256) void gram_softmax(
    const float* __restrict__ X, const float* __restrict__ Wq,
    const float* __restrict__ Wk, __hip_bfloat16* __restrict__ P, float scale)
{
  __shared__ float XR[64][33];
  __shared__ float XM[64][33];
  __shared__ float dqs[64];
  __shared__ float dks[N];
  int b = blockIdx.y, n0 = blockIdx.x * 64;
  int t = threadIdx.x, tx = t & 15, ty = t >> 4;
  const float* Xb = X + (size_t)b * N * D;
  if (t < 64) dqs[t] = Wq[(size_t)(n0 + t) * (N + 1)];
  for (int c = t; c < N; c += 256) dks[c] = Wk[(size_t)c * (N + 1)];
  __syncthreads();

  constexpr int NT = N / 64;
  float s[4][4 * NT];
  for (int mt = 0; mt < NT; ++mt) {
    int m0 = mt * 64;
    float acc[4][4] = {};
    for (int k0 = 0; k0 < D; k0 += 32) {
      int row = t >> 2, cs = (t & 3) * 8;
      const float* s1 = Xb + (size_t)(n0 + row) * D + k0 + cs;
      const float* s2 = Xb + (size_t)(m0 + row) * D + k0 + cs;
      float4 a0 = *(const float4*)s1;
      float4 a1 = *(const float4*)(s1 + 4);
      float4 b0 = *(const float4*)s2;
      float4 b1 = *(const float4*)(s2 + 4);
      XR[row][cs + 0] = a0.x; XR[row][cs + 1] = a0.y; XR[row][cs + 2] = a0.z; XR[row][cs + 3] = a0.w;
      XR[row][cs + 4] = a1.x; XR[row][cs + 5] = a1.y; XR[row][cs + 6] = a1.z; XR[row][cs + 7] = a1.w;
      XM[row][cs + 0] = b0.x; XM[row][cs + 1] = b0.y; XM[row][cs + 2] = b0.z; XM[row][cs + 3] = b0.w;
      XM[row][cs + 4] = b1.x; XM[row][cs + 5] = b1.y; XM[row][cs + 6] = b1.z; XM[row][cs + 7] = b1.w;
      __syncthreads();
#pragma unroll
      for (int kk = 0; kk < 32; ++kk) {
        float av[4], bv[4];
#pragma unroll
        for (int i = 0; i < 4; ++i) av[i] = XR[ty * 4 + i][kk];
#pragma unroll
        for (int j = 0; j < 4; ++j) bv[j] = XM[tx * 4 + j][kk];
#pragma unroll
        for (int i = 0; i < 4; ++i)
#pragma unroll
          for (int j = 0; j < 4; ++j) acc[i][j] += av[i] * bv[j];
      }
      __syncthreads();
    }
#pragma unroll
    for (int i = 0; i < 4; ++i)
#pragma unroll
      for (int j = 0; j < 4; ++j)
        s[i][mt * 4 + j] = acc[i][j] * dqs[ty * 4 + i] * dks[m0 + tx * 4 + j] * scale;
  }

#pragma unroll
  for (int i = 0; i < 4; ++i) {
    float mx = s[i][0];
#pragma unroll
    for (int q = 1; q < 4 * NT; ++q) mx = fmaxf(mx, s[i][q]);
#pragma unroll
    for (int off = 1; off < 16; off <<= 1) mx = fmaxf(mx, __shfl_xor(mx, off));
    float sum = 0.f;
#pragma unroll
    for (int q = 0; q < 4 * NT; ++q) { s[i][q] = __expf(s[i][q] - mx); sum += s[i][q]; }
#pragma unroll
    for (int off = 1; off < 16; off <<= 1) sum += __shfl_xor(sum, off);
    float inv = 1.0f / sum;
    __hip_bfloat16* Pr = P + (size_t)b * N * N + (size_t)(n0 + ty * 4 + i) * N;
#pragma unroll
    for (int mt = 0; mt < NT; ++mt) {
      uint2 pk;
      pk.x = pk2bf(s[i][mt * 4 + 0] * inv, s[i][mt * 4 + 1] * inv);
      pk.y = pk2bf(s[i][mt * 4 + 2] * inv, s[i][mt * 4 + 3] * inv);
      *(uint2*)(Pr + mt * 64 + tx * 4) = pk;
    }
  }
}

__global__ void reduceA(const __hip_bfloat16* __restrict__ P, float* __restrict__ A1,
                        float* __restrict__ A2, int N)
{
  int idx = blockIdx.x * 256 + threadIdx.x;
  size_t st = (size_t)N * N;
  const __hip_bfloat16* p = P + idx;
  float s = 0.f;
  for (int b = 0; b < NB; ++b) s += __bfloat162float(p[(size_t)b * st]);
  s *= (1.0f / NB);
  A1[idx] = s;
  A2[idx] = s;
}

__global__ void deg_dis(const float* __restrict__ A, float* __restrict__ dis, int N)
{
  int c = threadIdx.x;
  if (c < N) {
    float d = 0.f;
    for (int r = 0; r < N; ++r) d += A[r * N + c];
    dis[c] = (d > 0.f) ? (1.0f / sqrtf(d)) : 0.0f;
  }
}

// Bt_MT[n][n'] = dis[n]*dis[n']*A[n'][n]  (bf16, row-major) -- B^T operand of propagate
__global__ void mt_bf16(const float* __restrict__ A, const float* __restrict__ dis,
                        __hip_bfloat16* __restrict__ MT, int N)
{
  int idx = blockIdx.x * 256 + threadIdx.x;
  int c = idx / N, r = idx - c * N;
  MT[idx] = __float2bfloat16(dis[c] * dis[r] * A[r * N + c]);
}

// Wt[h][k] = bf16(W[k][h])
__global__ void wt_cast(const float* __restrict__ W, __hip_bfloat16* __restrict__ Wt,
                        int K, int H)
{
  int idx = blockIdx.x * 256 + threadIdx.x;
  int h = idx / K, k = idx - h * K;
  Wt[idx] = __float2bfloat16(W[(size_t)k * H + h]);
}

// f32 -> bf16 row-major copy (vectorized, 4 elems/thread)
__global__ void cast_bf16(const float* __restrict__ X, __hip_bfloat16* __restrict__ Y, int n4)
{
  int idx = blockIdx.x * 256 + threadIdx.x;
  if (idx < n4) {
    float4 v = ((const float4*)X)[idx];
    uint2 p;
    p.x = pk2bf(v.x, v.y);
    p.y = pk2bf(v.z, v.w);
    ((uint2*)Y)[idx] = p;
  }
}

// ---------------- MFMA GEMM: D = A * Bt^T, out = D^T row-major bf16 ----------------
// A [R][K] bf16 rm (batched if sA!=0), Bt [C][K] bf16 rm (shared ops pre-transposed),
// bias (f32, len R, indexed by D-row) added if non-null. Out[c][r] = D[r][c], [C][R] rm.
// Block 256 thr = 4 waves (2x2), tile 128x128, K-step 32, double-buffered LDS granules.
__global__ __launch_bounds__(256) void gemm_mfma(
    const __hip_bfloat16* __restrict__ A, long sA,
    const __hip_bfloat16* __restrict__ Bt, long sBt,
    const float* __restrict__ bias,
    __hip_bfloat16* __restrict__ Out, long sOut,
    int R, int K, int C, int tilesC)
{
  __shared__ unsigned short ldsA[2][4096];  // 8 frags x 1KB, fragment-linear granules
  __shared__ unsigned short ldsB[2][4096];
  int b = blockIdx.y;
  int tr = blockIdx.x / tilesC, tc = blockIdx.x - tr * tilesC;
  int t = threadIdx.x, l = t & 63, w = t >> 6;
  int wr = (w >> 1) * 64, wc = (w & 1) * 64;
  const __hip_bfloat16* Ab = A + (size_t)b * sA + (size_t)(tr * 128) * K;
  const __hip_bfloat16* Btb = Bt + (size_t)b * sBt + (size_t)(tc * 128) * K;

  f32x4 acc[4][4] = {};
  int lr = l & 15, lg = l >> 4;  // lane row-within-frag, k-granule
  int nk = K >> 5;

  // stage k-step ks into buf: wave w stages frags 2w,2w+1 of A and B panels.
  // granule (row f*16+lr, kg=lg) -> LDS offset f*512 + l*8 (fragment-linear, conflict-free)
#define STAGE(buf, ks)                                                              \
  {                                                                                 \
    int kk = (ks) * 32 + lg * 8;                                                    \
    _Pragma("unroll") for (int ff = 0; ff < 2; ++ff) {                              \
      int f = 2 * w + ff;                                                           \
      int row = f * 16 + lr;                                                        \
      *(uint4*)&ldsA[buf][f * 512 + l * 8] = *(const uint4*)(Ab + (size_t)row * K + kk); \
      *(uint4*)&ldsB[buf][f * 512 + l * 8] = *(const uint4*)(Btb + (size_t)row * K + kk);\
    }                                                                               \
  }

  STAGE(0, 0)
  __syncthreads();
  for (int ks = 0; ks < nk; ++ks) {
    int buf = ks & 1;
    if (ks + 1 < nk) STAGE((ks + 1) & 1, ks + 1)
    short8v a[4], bq[4];
#pragma unroll
    for (int i = 0; i < 4; ++i)
      a[i] = *(const short8v*)&ldsA[buf][((wr >> 4) + i) * 512 + l * 8];
#pragma unroll
    for (int j = 0; j < 4; ++j)
      bq[j] = *(const short8v*)&ldsB[buf][((wc >> 4) + j) * 512 + l * 8];
#pragma unroll
    for (int i = 0; i < 4; ++i)
#pragma unroll
      for (int j = 0; j < 4; ++j)
        acc[i][j] = __builtin_amdgcn_mfma_f32_16x16x32_bf16(a[i], bq[j], acc[i][j], 0, 0, 0);
    __syncthreads();
  }

  // epilogue: lane holds D rows r0..r0+3 (contiguous) at col c -> 8B store to Out[c][r0]
  __hip_bfloat16* Ob = Out + (size_t)b * sOut;
#pragma unroll
  for (int i = 0; i < 4; ++i) {
#pragma unroll
    for (int j = 0; j < 4; ++j) {
      int r = tr * 128 + wr + i * 16 + lg * 4;
      int c = tc * 128 + wc + j * 16 + lr;
      f32x4 v = acc[i][j];
      if (bias) {
        v[0] += bias[r + 0];
        v[1] += bias[r + 1];
        v[2] += bias[r + 2];
        v[3] += bias[r + 3];
      }
      uint2 p;
      p.x = pk2bf(v[0], v[1]);
      p.y = pk2bf(v[2], v[3]);
      *(uint2*)(Ob + (size_t)c * R + r) = p;
    }
  }
}

// out[b][h] = mean_n H[b][n][h], H bf16 [N][128] rm
__global__ void mean_nodes(const __hip_bfloat16* __restrict__ Hb, float* __restrict__ out, int N)
{
  int b = blockIdx.x, h = threadIdx.x;  // 128 threads
  const __hip_bfloat16* p = Hb + (size_t)b * N * 128 + h;
  float s = 0.f;
  for (int c = 0; c < N; ++c) s += __bfloat162float(p[c * 128]);
  out[b * 128 + h] = s * (1.0f / N);
}

__global__ void proj_kernel(const float* __restrict__ of, const float* __restrict__ ot,
                            const float* __restrict__ pw, const float* __restrict__ pb,
                            float* __restrict__ out)
{
  int idx = blockIdx.x * 256 + threadIdx.x;  // < 512*64
  int b = idx >> 6, o = idx & 63;
  float s = pb[o];
  const float* f = of + b * 128;
  const float* tt = ot + b * 128;
#pragma unroll 4
  for (int j = 0; j < 128; ++j) s += f[j] * pw[j * 64 + o];
#pragma unroll 4
  for (int j = 0; j < 128; ++j) s += tt[j] * pw[(128 + j) * 64 + o];
  out[idx] = s;
}

extern "C" void kernel_launch(void* const* d_in, const int* in_sizes, int n_in,
                              void* d_out, int out_size, void* d_ws, size_t ws_size,
                              hipStream_t stream)
{
  const float* X_time = (const float*)d_in[0];
  const float* conv_w = (const float*)d_in[1];
  const float* conv_b = (const float*)d_in[2];
  const float* wq_feat = (const float*)d_in[3];
  const float* wk_feat = (const float*)d_in[4];
  const float* wq_time = (const float*)d_in[5];
  const float* wk_time = (const float*)d_in[6];
  const float* gf1_w = (const float*)d_in[7];
  const float* gf1_b = (const float*)d_in[8];
  const float* gf2_w = (const float*)d_in[9];
  const float* gf2_b = (const float*)d_in[10];
  const float* gf3_w = (const float*)d_in[11];
  const float* gf3_b = (const float*)d_in[12];
  const float* gt1_w = (const float*)d_in[13];
  const float* gt1_b = (const float*)d_in[14];
  const float* gt2_w = (const float*)d_in[15];
  const float* gt2_b = (const float*)d_in[16];
  const float* gt3_w = (const float*)d_in[17];
  const float* gt3_b = (const float*)d_in[18];
  const float* proj_w = (const float*)d_in[19];
  const float* proj_b = (const float*)d_in[20];

  typedef __hip_bfloat16 bf16;
  char* ws = (char*)d_ws;
  const size_t MiB = 1ull << 20;
  // region0 (68MiB): XF_f32 (64MiB), later GCN ping-pong buffers
  // region1 (68MiB): P_time (64MiB)
  // region2 (17MiB): P_feat (16MiB)
  // region3 (34MiB): XF_bf16 (32MiB), later X_time bf16 (32MiB)
  // region4: smalls
  float* XFf = (float*)ws;                                   // 0
  bf16* Pt = (bf16*)(ws + 68 * MiB);
  bf16* Pf = (bf16*)(ws + 136 * MiB);
  bf16* XFb = (bf16*)(ws + 153 * MiB);
  bf16* Xtb = (bf16*)(ws + 153 * MiB);                       // reused after G1
  char* SM = ws + 187 * MiB;
  float* A_feat = (float*)SM;                                // 64KB
  float* A_time = (float*)(SM + 65536);                      // 256KB
  float* dis_f = (float*)(SM + 327680);                      // +2KB
  float* dis_t = (float*)(SM + 329728);
  bf16* MTf = (bf16*)(SM + 331776);                          // 32KB
  bf16* MTt = (bf16*)(SM + 364544);                          // 128KB
  bf16* w1f = (bf16*)(SM + 495616);                          // 64KB (gf1_wt 128x256)
  bf16* w2f = (bf16*)(SM + 561152);                          // 32KB each below
  bf16* w3f = (bf16*)(SM + 593920);
  bf16* w1t = (bf16*)(SM + 626688);
  bf16* w2t = (bf16*)(SM + 659456);
  bf16* w3t = (bf16*)(SM + 692224);
  float* out_f = (float*)(SM + 724992);                      // 256KB
  float* out_t = (float*)(SM + 987136);                      // 256KB
  // GCN ping-pong in region0:
  bf16* F0 = (bf16*)ws;                                      // 16MiB
  bf16* F1 = (bf16*)(ws + 17 * MiB);                         // 16MiB
  bf16* T0 = (bf16*)ws;                                      // 32MiB
  bf16* T1 = (bf16*)(ws + 34 * MiB);                         // 32MiB

  float* out = (float*)d_out;
  float* outA_f = out + 32768;
  float* outA_t = out + 49152;

  // 1) conv: X_time (reshaped [b][128][256]) -> XF f32 + bf16
  conv_kernel<<<dim3(2, NB), 256, 0, stream>>>(X_time, conv_w, conv_b, XFf, XFb);
  // 2) grams + per-batch softmax (f32 compute, bf16 P)
  gram_softmax<128, 256><<<dim3(2, NB), 256, 0, stream>>>(XFf, wq_feat, wk_feat, Pf, 0.0625f);
  gram_softmax<256, 128><<<dim3(4, NB), 256, 0, stream>>>(X_time, wq_time, wk_time, Pt,
                                                          0.08838834764831845f);
  // 3) batch mean -> A (ws + d_out)
  reduceA<<<64, 256, 0, stream>>>(Pf, A_feat, outA_f, 128);
  reduceA<<<256, 256, 0, stream>>>(Pt, A_time, outA_t, 256);
  // 4) normalized adjacency (bf16 B^T operand) + shared weight transposes
  deg_dis<<<1, 128, 0, stream>>>(A_feat, dis_f, 128);
  deg_dis<<<1, 256, 0, stream>>>(A_time, dis_t, 256);
  mt_bf16<<<64, 256, 0, stream>>>(A_feat, dis_f, MTf, 128);
  mt_bf16<<<256, 256, 0, stream>>>(A_time, dis_t, MTt, 256);
  wt_cast<<<128, 256, 0, stream>>>(gf1_w, w1f, 256, 128);
  wt_cast<<<64, 256, 0, stream>>>(gf2_w, w2f, 128, 128);
  wt_cast<<<64, 256, 0, stream>>>(gf3_w, w3f, 128, 128);
  wt_cast<<<64, 256, 0, stream>>>(gt1_w, w1t, 128, 128);
  wt_cast<<<64, 256, 0, stream>>>(gt2_w, w2t, 128, 128);
  wt_cast<<<64, 256, 0, stream>>>(gt3_w, w3t, 128, 128);

  // 5) feat GCN (N=128): out stored transposed each step; chain closes exactly.
  gemm_mfma<<<dim3(1, NB), 256, 0, stream>>>(XFb, 32768, w1f, 0, nullptr, F0, 16384, 128, 256, 128, 1);
  cast_bf16<<<16384, 256, 0, stream>>>(X_time, Xtb, NB * WD * NF / 4);  // region3 reuse after G1
  gemm_mfma<<<dim3(1, NB), 256, 0, stream>>>(F0, 16384, MTf, 0, gf1_b, F1, 16384, 128, 128, 128, 1);
  gemm_mfma<<<dim3(1, NB), 256, 0, stream>>>(F1, 16384, w2f, 0, nullptr, F0, 16384, 128, 128, 128, 1);
  gemm_mfma<<<dim3(1, NB), 256, 0, stream>>>(F0, 16384, MTf, 0, gf2_b, F1, 16384, 128, 128, 128, 1);
  gemm_mfma<<<dim3(1, NB), 256, 0, stream>>>(F1, 16384, w3f, 0, nullptr, F0, 16384, 128, 128, 128, 1);
  gemm_mfma<<<dim3(1, NB), 256, 0, stream>>>(F0, 16384, MTf, 0, gf3_b, F1, 16384, 128, 128, 128, 1);
  mean_nodes<<<NB, 128, 0, stream>>>(F1, out_f, 128);

  // 6) time GCN (N=256)
  gemm_mfma<<<dim3(2, NB), 256, 0, stream>>>(Xtb, 32768, w1t, 0, nullptr, T0, 32768, 256, 128, 128, 1);
  gemm_mfma<<<dim3(2, NB), 256, 0, stream>>>(T0, 32768, MTt, 0, gt1_b, T1, 32768, 128, 256, 256, 2);
  gemm_mfma<<<dim3(2, NB), 256, 0, stream>>>(T1, 32768, w2t, 0, nullptr, T0, 32768, 256, 128, 128, 1);
  gemm_mfma<<<dim3(2, NB), 256, 0, stream>>>(T0, 32768, MTt, 0, gt2_b, T1, 32768, 128, 256, 256, 2);
  gemm_mfma<<<dim3(2, NB), 256, 0, stream>>>(T1, 32768, w3t, 0, nullptr, T0, 32768, 256, 128, 128, 1);
  gemm_mfma<<<dim3(2, NB), 256, 0, stream>>>(T0, 32768, MTt, 0, gt3_b, T1, 32768, 128, 256, 256, 2);
  mean_nodes<<<NB, 128, 0, stream>>>(T1, out_t, 256);

  // 7) projection
  proj_kernel<<<128, 256, 0, stream>>>(out_f, out_t, proj_w, proj_b, out);
}

// Round 4
// 850.232 us; speedup vs baseline: 2.4805x; 1.3078x over previous
//
#include <hip/hip_runtime.h>
#include <hip/hip_bf16.h>

#define NB 512
#define WD 256
#define NF 128

typedef __attribute__((ext_vector_type(8))) short short8v;
typedef __attribute__((ext_vector_type(4))) float f32x4;

__device__ inline unsigned pk2bf(float a, float b) {
  __hip_bfloat162 h;
  h.x = __float2bfloat16(a);
  h.y = __float2bfloat16(b);
  unsigned r;
  __builtin_memcpy(&r, &h, 4);
  return r;
}

// ---------------- conv1d causal (dilated, pad 4, dil 2, K=3) ----------------
// Y[b][o][l] = conv_b[o] + sum_i sum_k W[o][i][k] * X[b][i][l-4+2k]  (zero pad)
// bf16 output only (grams + GCN both consume bf16 now).
__global__ __launch_bounds__(256) void conv_kernel(
    const float* __restrict__ X, const float* __restrict__ W,
    const float* __restrict__ bias, __hip_bfloat16* __restrict__ Yb)
{
  __shared__ float Xs[16][264];   // cols 0..3 = zero halo
  __shared__ float Ws2[48][66];   // [local_i*3+k][o]
  int b = blockIdx.y;
  int o0 = blockIdx.x * 64;
  int t = threadIdx.x, tx = t & 15, ty = t >> 4;
  const float* Xb = X + (size_t)b * (NF * WD);
  float acc[4][16] = {};
  if (t < 16) *(float4*)&Xs[t][0] = make_float4(0.f, 0.f, 0.f, 0.f);
  for (int i0 = 0; i0 < NF; i0 += 16) {
    {
      const float* src = Xb + (size_t)(i0 + ty) * WD;
#pragma unroll
      for (int j = 0; j < 4; ++j) {
        int col4 = tx + 16 * j;
        *(float4*)&Xs[ty][4 + col4 * 4] = *(const float4*)(src + col4 * 4);
      }
    }
    {
      int o = t >> 2, q = t & 3;
      const float* wsrc = W + (size_t)(o0 + o) * 384 + i0 * 3;
#pragma unroll
      for (int m = 0; m < 3; ++m) {
        int c4 = q + 4 * m;
        float4 w = *(const float4*)(wsrc + c4 * 4);
        Ws2[c4 * 4 + 0][o] = w.x;
        Ws2[c4 * 4 + 1][o] = w.y;
        Ws2[c4 * 4 + 2][o] = w.z;
        Ws2[c4 * 4 + 3][o] = w.w;
      }
    }
    __syncthreads();
#pragma unroll 2   // NOT full unroll: full unroll -> 256 VGPR + scratch spill (R2: 711MB spill writes)
    for (int ii = 0; ii < 16; ++ii) {
      float w0[4], w1[4], w2[4];
#pragma unroll
      for (int oy = 0; oy < 4; ++oy) {
        w0[oy] = Ws2[ii * 3 + 0][ty * 4 + oy];
        w1[oy] = Ws2[ii * 3 + 1][ty * 4 + oy];
        w2[oy] = Ws2[ii * 3 + 2][ty * 4 + oy];
      }
#pragma unroll
      for (int g = 0; g < 4; ++g) {
        float x[8];
        *(float4*)&x[0] = *(const float4*)&Xs[ii][g * 64 + tx * 4];
        *(float4*)&x[4] = *(const float4*)&Xs[ii][g * 64 + tx * 4 + 4];
#pragma unroll
        for (int oy = 0; oy < 4; ++oy)
#pragma unroll
          for (int j = 0; j < 4; ++j)
            acc[oy][g * 4 + j] += w0[oy] * x[j] + w1[oy] * x[j + 2] + w2[oy] * x[j + 4];
      }
    }
    __syncthreads();
  }
#pragma unroll
  for (int oy = 0; oy < 4; ++oy) {
    int o = o0 + ty * 4 + oy;
    float bv = bias[o];
    __hip_bfloat16* Yr2 = Yb + (size_t)b * (NF * WD) + (size_t)o * WD;
#pragma unroll
    for (int g = 0; g < 4; ++g) {
      uint2 p;
      p.x = pk2bf(acc[oy][g * 4 + 0] + bv, acc[oy][g * 4 + 1] + bv);
      p.y = pk2bf(acc[oy][g * 4 + 2] + bv, acc[oy][g * 4 + 3] + bv);
      *(uint2*)(Yr2 + g * 64 + tx * 4) = p;
    }
  }
}

// ---------------- MFMA gram + row softmax ----------------
// S[n][m] = dq[n]*dk[m]*(X[b,n,:].X[b,m,:])*scale; P[b] = softmax_m(S), bf16.
// Block = 4 waves; wave owns 16 rows x all N cols. LDS-free: frags direct from
// global (L2/L3-resident). C/D 16x16 layout: col=lane&15, row=(lane>>4)*4+reg
// -> row softmax = per-lane reduce over NT regs + 16-lane shfl_xor.
template <int N, int D>
__global__ __launch_bounds__(256) void gram_mfma(
    const __hip_bfloat16* __restrict__ X, const float* __restrict__ Wq,
    const float* __restrict__ Wk, __hip_bfloat16* __restrict__ P, float scale)
{
  constexpr int NT = N / 16;   // col tiles
  constexpr int KS = D / 32;   // k steps
  int b = blockIdx.y;
  int t = threadIdx.x, l = t & 63, w = t >> 6;
  int lr = l & 15, lg = l >> 4;
  int rowbase = blockIdx.x * 64 + w * 16;
  const __hip_bfloat16* Xb = X + (size_t)b * N * D;

  f32x4 acc[NT] = {};
#pragma unroll
  for (int ks = 0; ks < KS; ++ks) {
    short8v a = *(const short8v*)(Xb + (size_t)(rowbase + lr) * D + ks * 32 + lg * 8);
#pragma unroll
    for (int m = 0; m < NT; ++m) {
      short8v bb = *(const short8v*)(Xb + (size_t)(m * 16 + lr) * D + ks * 32 + lg * 8);
      acc[m] = __builtin_amdgcn_mfma_f32_16x16x32_bf16(a, bb, acc[m], 0, 0, 0);
    }
  }

  float dkr[NT];
#pragma unroll
  for (int m = 0; m < NT; ++m) dkr[m] = Wk[(size_t)(m * 16 + lr) * (N + 1)] * scale;

#pragma unroll
  for (int i = 0; i < 4; ++i) {
    int row = rowbase + lg * 4 + i;
    float dq = Wq[(size_t)row * (N + 1)];
    float v[NT];
    float mx = -3.0e38f;
#pragma unroll
    for (int m = 0; m < NT; ++m) {
      v[m] = acc[m][i] * dq * dkr[m];
      mx = fmaxf(mx, v[m]);
    }
#pragma unroll
    for (int off = 1; off < 16; off <<= 1) mx = fmaxf(mx, __shfl_xor(mx, off));
    float sum = 0.f;
#pragma unroll
    for (int m = 0; m < NT; ++m) { v[m] = __expf(v[m] - mx); sum += v[m]; }
#pragma unroll
    for (int off = 1; off < 16; off <<= 1) sum += __shfl_xor(sum, off);
    float inv = 1.0f / sum;
    __hip_bfloat16* Pr = P + (size_t)b * N * N + (size_t)row * N + lr;
#pragma unroll
    for (int m = 0; m < NT; ++m) Pr[m * 16] = __float2bfloat16(v[m] * inv);
  }
}

__global__ void reduceA(const __hip_bfloat16* __restrict__ P, float* __restrict__ A1,
                        float* __restrict__ A2, int N)
{
  int idx = blockIdx.x * 256 + threadIdx.x;
  size_t st = (size_t)N * N;
  const __hip_bfloat16* p = P + idx;
  float s = 0.f;
  for (int b = 0; b < NB; ++b) s += __bfloat162float(p[(size_t)b * st]);
  s *= (1.0f / NB);
  A1[idx] = s;
  A2[idx] = s;
}

__global__ void deg_dis(const float* __restrict__ A, float* __restrict__ dis, int N)
{
  int c = threadIdx.x;
  if (c < N) {
    float d = 0.f;
    for (int r = 0; r < N; ++r) d += A[r * N + c];
    dis[c] = (d > 0.f) ? (1.0f / sqrtf(d)) : 0.0f;
  }
}

// Bt_MT[n][n'] = dis[n]*dis[n']*A[n'][n]  (bf16, row-major) -- B^T operand of propagate
__global__ void mt_bf16(const float* __restrict__ A, const float* __restrict__ dis,
                        __hip_bfloat16* __restrict__ MT, int N)
{
  int idx = blockIdx.x * 256 + threadIdx.x;
  int c = idx / N, r = idx - c * N;
  MT[idx] = __float2bfloat16(dis[c] * dis[r] * A[r * N + c]);
}

// Wt[h][k] = bf16(W[k][h])
__global__ void wt_cast(const float* __restrict__ W, __hip_bfloat16* __restrict__ Wt,
                        int K, int H)
{
  int idx = blockIdx.x * 256 + threadIdx.x;
  int h = idx / K, k = idx - h * K;
  Wt[idx] = __float2bfloat16(W[(size_t)k * H + h]);
}

// f32 -> bf16 row-major copy (vectorized, 4 elems/thread)
__global__ void cast_bf16(const float* __restrict__ X, __hip_bfloat16* __restrict__ Y, int n4)
{
  int idx = blockIdx.x * 256 + threadIdx.x;
  if (idx < n4) {
    float4 v = ((const float4*)X)[idx];
    uint2 p;
    p.x = pk2bf(v.x, v.y);
    p.y = pk2bf(v.z, v.w);
    ((uint2*)Y)[idx] = p;
  }
}

// ---------------- MFMA GEMM: D = A * Bt^T, out = D^T row-major bf16 ----------------
__global__ __launch_bounds__(256) void gemm_mfma(
    const __hip_bfloat16* __restrict__ A, long sA,
    const __hip_bfloat16* __restrict__ Bt, long sBt,
    const float* __restrict__ bias,
    __hip_bfloat16* __restrict__ Out, long sOut,
    int R, int K, int C, int tilesC)
{
  __shared__ unsigned short ldsA[2][4096];  // 8 frags x 1KB, fragment-linear granules
  __shared__ unsigned short ldsB[2][4096];
  int b = blockIdx.y;
  int tr = blockIdx.x / tilesC, tc = blockIdx.x - tr * tilesC;
  int t = threadIdx.x, l = t & 63, w = t >> 6;
  int wr = (w >> 1) * 64, wc = (w & 1) * 64;
  const __hip_bfloat16* Ab = A + (size_t)b * sA + (size_t)(tr * 128) * K;
  const __hip_bfloat16* Btb = Bt + (size_t)b * sBt + (size_t)(tc * 128) * K;

  f32x4 acc[4][4] = {};
  int lr = l & 15, lg = l >> 4;
  int nk = K >> 5;

#define STAGE(buf, ks)                                                              \
  {                                                                                 \
    int kk = (ks) * 32 + lg * 8;                                                    \
    _Pragma("unroll") for (int ff = 0; ff < 2; ++ff) {                              \
      int f = 2 * w + ff;                                                           \
      int row = f * 16 + lr;                                                        \
      *(uint4*)&ldsA[buf][f * 512 + l * 8] = *(const uint4*)(Ab + (size_t)row * K + kk); \
      *(uint4*)&ldsB[buf][f * 512 + l * 8] = *(const uint4*)(Btb + (size_t)row * K + kk);\
    }                                                                               \
  }

  STAGE(0, 0)
  __syncthreads();
  for (int ks = 0; ks < nk; ++ks) {
    int buf = ks & 1;
    if (ks + 1 < nk) STAGE((ks + 1) & 1, ks + 1)
    short8v a[4], bq[4];
#pragma unroll
    for (int i = 0; i < 4; ++i)
      a[i] = *(const short8v*)&ldsA[buf][((wr >> 4) + i) * 512 + l * 8];
#pragma unroll
    for (int j = 0; j < 4; ++j)
      bq[j] = *(const short8v*)&ldsB[buf][((wc >> 4) + j) * 512 + l * 8];
#pragma unroll
    for (int i = 0; i < 4; ++i)
#pragma unroll
      for (int j = 0; j < 4; ++j)
        acc[i][j] = __builtin_amdgcn_mfma_f32_16x16x32_bf16(a[i], bq[j], acc[i][j], 0, 0, 0);
    __syncthreads();
  }

  __hip_bfloat16* Ob = Out + (size_t)b * sOut;
#pragma unroll
  for (int i = 0; i < 4; ++i) {
#pragma unroll
    for (int j = 0; j < 4; ++j) {
      int r = tr * 128 + wr + i * 16 + lg * 4;
      int c = tc * 128 + wc + j * 16 + lr;
      f32x4 v = acc[i][j];
      if (bias) {
        v[0] += bias[r + 0];
        v[1] += bias[r + 1];
        v[2] += bias[r + 2];
        v[3] += bias[r + 3];
      }
      uint2 p;
      p.x = pk2bf(v[0], v[1]);
      p.y = pk2bf(v[2], v[3]);
      *(uint2*)(Ob + (size_t)c * R + r) = p;
    }
  }
}

// out[b][h] = mean_n H[b][n][h], H bf16 [N][128] rm
__global__ void mean_nodes(const __hip_bfloat16* __restrict__ Hb, float* __restrict__ out, int N)
{
  int b = blockIdx.x, h = threadIdx.x;  // 128 threads
  const __hip_bfloat16* p = Hb + (size_t)b * N * 128 + h;
  float s = 0.f;
  for (int c = 0; c < N; ++c) s += __bfloat162float(p[c * 128]);
  out[b * 128 + h] = s * (1.0f / N);
}

__global__ void proj_kernel(const float* __restrict__ of, const float* __restrict__ ot,
                            const float* __restrict__ pw, const float* __restrict__ pb,
                            float* __restrict__ out)
{
  int idx = blockIdx.x * 256 + threadIdx.x;  // < 512*64
  int b = idx >> 6, o = idx & 63;
  float s = pb[o];
  const float* f = of + b * 128;
  const float* tt = ot + b * 128;
#pragma unroll 4
  for (int j = 0; j < 128; ++j) s += f[j] * pw[j * 64 + o];
#pragma unroll 4
  for (int j = 0; j < 128; ++j) s += tt[j] * pw[(128 + j) * 64 + o];
  out[idx] = s;
}

extern "C" void kernel_launch(void* const* d_in, const int* in_sizes, int n_in,
                              void* d_out, int out_size, void* d_ws, size_t ws_size,
                              hipStream_t stream)
{
  const float* X_time = (const float*)d_in[0];
  const float* conv_w = (const float*)d_in[1];
  const float* conv_b = (const float*)d_in[2];
  const float* wq_feat = (const float*)d_in[3];
  const float* wk_feat = (const float*)d_in[4];
  const float* wq_time = (const float*)d_in[5];
  const float* wk_time = (const float*)d_in[6];
  const float* gf1_w = (const float*)d_in[7];
  const float* gf1_b = (const float*)d_in[8];
  const float* gf2_w = (const float*)d_in[9];
  const float* gf2_b = (const float*)d_in[10];
  const float* gf3_w = (const float*)d_in[11];
  const float* gf3_b = (const float*)d_in[12];
  const float* gt1_w = (const float*)d_in[13];
  const float* gt1_b = (const float*)d_in[14];
  const float* gt2_w = (const float*)d_in[15];
  const float* gt2_b = (const float*)d_in[16];
  const float* gt3_w = (const float*)d_in[17];
  const float* gt3_b = (const float*)d_in[18];
  const float* proj_w = (const float*)d_in[19];
  const float* proj_b = (const float*)d_in[20];

  typedef __hip_bfloat16 bf16;
  char* ws = (char*)d_ws;
  const size_t MiB = 1ull << 20;
  // Layout (MiB): 0..32 XFb (later T0), 34..66 Xtb (later T1),
  //               68..132 Pt (later F0@68, F1@102), 136..152 Pf, 187+ smalls
  bf16* XFb = (bf16*)ws;
  bf16* Xtb = (bf16*)(ws + 34 * MiB);
  bf16* Pt = (bf16*)(ws + 68 * MiB);
  bf16* Pf = (bf16*)(ws + 136 * MiB);
  bf16* F0 = (bf16*)(ws + 68 * MiB);
  bf16* F1 = (bf16*)(ws + 102 * MiB);
  bf16* T0 = (bf16*)ws;
  bf16* T1 = (bf16*)(ws + 34 * MiB);
  char* SM = ws + 187 * MiB;
  float* A_feat = (float*)SM;                                // 64KB
  float* A_time = (float*)(SM + 65536);                      // 256KB
  float* dis_f = (float*)(SM + 327680);
  float* dis_t = (float*)(SM + 329728);
  bf16* MTf = (bf16*)(SM + 331776);                          // 32KB
  bf16* MTt = (bf16*)(SM + 364544);                          // 128KB
  bf16* w1f = (bf16*)(SM + 495616);                          // 64KB
  bf16* w2f = (bf16*)(SM + 561152);
  bf16* w3f = (bf16*)(SM + 593920);
  bf16* w1t = (bf16*)(SM + 626688);
  bf16* w2t = (bf16*)(SM + 659456);
  bf16* w3t = (bf16*)(SM + 692224);
  float* out_f = (float*)(SM + 724992);
  float* out_t = (float*)(SM + 987136);

  float* out = (float*)d_out;
  float* outA_f = out + 32768;
  float* outA_t = out + 49152;

  // 1) casts + conv (bf16 everywhere downstream)
  cast_bf16<<<16384, 256, 0, stream>>>(X_time, Xtb, NB * WD * NF / 4);
  conv_kernel<<<dim3(2, NB), 256, 0, stream>>>(X_time, conv_w, conv_b, XFb);
  // 2) MFMA grams + per-batch softmax
  gram_mfma<128, 256><<<dim3(2, NB), 256, 0, stream>>>(XFb, wq_feat, wk_feat, Pf, 0.0625f);
  gram_mfma<256, 128><<<dim3(4, NB), 256, 0, stream>>>(Xtb, wq_time, wk_time, Pt,
                                                       0.08838834764831845f);
  // 3) batch mean -> A (ws + d_out)
  reduceA<<<64, 256, 0, stream>>>(Pf, A_feat, outA_f, 128);
  reduceA<<<256, 256, 0, stream>>>(Pt, A_time, outA_t, 256);
  // 4) normalized adjacency (bf16 B^T operand) + shared weight transposes
  deg_dis<<<1, 128, 0, stream>>>(A_feat, dis_f, 128);
  deg_dis<<<1, 256, 0, stream>>>(A_time, dis_t, 256);
  mt_bf16<<<64, 256, 0, stream>>>(A_feat, dis_f, MTf, 128);
  mt_bf16<<<256, 256, 0, stream>>>(A_time, dis_t, MTt, 256);
  wt_cast<<<128, 256, 0, stream>>>(gf1_w, w1f, 256, 128);
  wt_cast<<<64, 256, 0, stream>>>(gf2_w, w2f, 128, 128);
  wt_cast<<<64, 256, 0, stream>>>(gf3_w, w3f, 128, 128);
  wt_cast<<<64, 256, 0, stream>>>(gt1_w, w1t, 128, 128);
  wt_cast<<<64, 256, 0, stream>>>(gt2_w, w2t, 128, 128);
  wt_cast<<<64, 256, 0, stream>>>(gt3_w, w3t, 128, 128);

  // 5) feat GCN (N=128): Pf region free after reduceA -> F0/F1 in Pt region
  gemm_mfma<<<dim3(1, NB), 256, 0, stream>>>(XFb, 32768, w1f, 0, nullptr, F0, 16384, 128, 256, 128, 1);
  gemm_mfma<<<dim3(1, NB), 256, 0, stream>>>(F0, 16384, MTf, 0, gf1_b, F1, 16384, 128, 128, 128, 1);
  gemm_mfma<<<dim3(1, NB), 256, 0, stream>>>(F1, 16384, w2f, 0, nullptr, F0, 16384, 128, 128, 128, 1);
  gemm_mfma<<<dim3(1, NB), 256, 0, stream>>>(F0, 16384, MTf, 0, gf2_b, F1, 16384, 128, 128, 128, 1);
  gemm_mfma<<<dim3(1, NB), 256, 0, stream>>>(F1, 16384, w3f, 0, nullptr, F0, 16384, 128, 128, 128, 1);
  gemm_mfma<<<dim3(1, NB), 256, 0, stream>>>(F0, 16384, MTf, 0, gf3_b, F1, 16384, 128, 128, 128, 1);
  mean_nodes<<<NB, 128, 0, stream>>>(F1, out_f, 128);

  // 6) time GCN (N=256): T0 reuses XFb region (feat G1 done), T1 reuses Xtb after time G1
  gemm_mfma<<<dim3(2, NB), 256, 0, stream>>>(Xtb, 32768, w1t, 0, nullptr, T0, 32768, 256, 128, 128, 1);
  gemm_mfma<<<dim3(2, NB), 256, 0, stream>>>(T0, 32768, MTt, 0, gt1_b, T1, 32768, 128, 256, 256, 2);
  gemm_mfma<<<dim3(2, NB), 256, 0, stream>>>(T1, 32768, w2t, 0, nullptr, T0, 32768, 256, 128, 128, 1);
  gemm_mfma<<<dim3(2, NB), 256, 0, stream>>>(T0, 32768, MTt, 0, gt2_b, T1, 32768, 128, 256, 256, 2);
  gemm_mfma<<<dim3(2, NB), 256, 0, stream>>>(T1, 32768, w3t, 0, nullptr, T0, 32768, 256, 128, 128, 1);
  gemm_mfma<<<dim3(2, NB), 256, 0, stream>>>(T0, 32768, MTt, 0, gt3_b, T1, 32768, 128, 256, 256, 2);
  mean_nodes<<<NB, 128, 0, stream>>>(T1, out_t, 256);

  // 7) projection
  proj_kernel<<<128, 256, 0, stream>>>(out_f, out_t, proj_w, proj_b, out);
}

// Round 5
// 742.321 us; speedup vs baseline: 2.8411x; 1.1454x over previous
//
#include <hip/hip_runtime.h>
#include <hip/hip_bf16.h>

#define NB 512
#define WD 256
#define NF 128

typedef __attribute__((ext_vector_type(8))) short short8v;
typedef __attribute__((ext_vector_type(4))) float f32x4;

__device__ inline unsigned pk2bf(float a, float b) {
  __hip_bfloat162 h;
  h.x = __float2bfloat16(a);
  h.y = __float2bfloat16(b);
  unsigned r;
  __builtin_memcpy(&r, &h, 4);
  return r;
}

// ---------------- prep: bf16 flat cast + bf16 transpose ----------------
// Xflat[b][w][f] = bf16(X_time flat)   (time-branch operand)
// Xt[b][l][i]    = bf16(X[b][i][l])    (conv im2col A-operand; X = [128][256] view)
__global__ __launch_bounds__(256) void prep_x(
    const float* __restrict__ X, __hip_bfloat16* __restrict__ Xflat,
    __hip_bfloat16* __restrict__ Xt)
{
  int b = blockIdx.x;
  const float* Xb = X + (size_t)b * 32768;
  __hip_bfloat16* Fb = Xflat + (size_t)b * 32768;
  __hip_bfloat16* Tb = Xt + (size_t)b * 32768;
  int t = threadIdx.x;
  for (int idx = t; idx < 8192; idx += 256) {
    float4 v = ((const float4*)Xb)[idx];
    uint2 p;
    p.x = pk2bf(v.x, v.y);
    p.y = pk2bf(v.z, v.w);
    ((uint2*)Fb)[idx] = p;
  }
  __shared__ float tile[32][33];
  int tr = t & 31, tc = t >> 5;  // 32 x 8
  for (int tt = 0; tt < 32; ++tt) {
    int r0 = (tt >> 3) * 32, c0 = (tt & 7) * 32;
    __syncthreads();
#pragma unroll
    for (int rr = tc; rr < 32; rr += 8)
      tile[rr][tr] = Xb[(size_t)(r0 + rr) * 256 + c0 + tr];
    __syncthreads();
#pragma unroll
    for (int rr = tc; rr < 32; rr += 8)
      Tb[(size_t)(c0 + rr) * 128 + r0 + tr] = __float2bfloat16(tile[tr][rr]);
  }
}

// Wc[o][k*128+i] = bf16(conv_w[o][i][k])  -- B^T operand of conv GEMM
__global__ void wc_cast(const float* __restrict__ W, __hip_bfloat16* __restrict__ Wc)
{
  int idx = blockIdx.x * 256 + threadIdx.x;  // 128*384
  int o = idx / 384, rem = idx - o * 384;
  int k = rem >> 7, i = rem & 127;
  Wc[idx] = __float2bfloat16(W[(size_t)o * 384 + i * 3 + k]);
}

// ---------------- conv as MFMA GEMM ----------------
// D[l][o] = sum_{k,i} Xt[l+2k-4][i] * Wc[o][k*128+i]  (zero rows for l+2k-4 < 0)
// Out[b][o][l] = D[l][o] + conv_b[o]   ([128][256] row-major bf16 = XFb)
__global__ __launch_bounds__(256) void conv_gemm(
    const __hip_bfloat16* __restrict__ Xt, const __hip_bfloat16* __restrict__ Wc,
    const float* __restrict__ bias, __hip_bfloat16* __restrict__ Out)
{
  __shared__ unsigned short ldsA[2][4096];
  __shared__ unsigned short ldsB[2][4096];
  int b = blockIdx.y;
  int trt = blockIdx.x;  // l-tile 0..1
  int t = threadIdx.x, l = t & 63, w = t >> 6;
  int wr = (w >> 1) * 64, wcc = (w & 1) * 64;
  int lr = l & 15, lg = l >> 4;
  const __hip_bfloat16* Ab = Xt + (size_t)b * 32768;
  f32x4 acc[4][4] = {};

#define CSTAGE(buf, ks)                                                               \
  {                                                                                   \
    int kgrp = (ks) >> 2;                                                             \
    int kk = ((ks) & 3) * 32 + lg * 8;                                                \
    _Pragma("unroll") for (int ff = 0; ff < 2; ++ff) {                                \
      int f = 2 * w + ff;                                                             \
      int lrow = trt * 128 + f * 16 + lr + 2 * kgrp - 4;                              \
      uint4 ga = make_uint4(0, 0, 0, 0);                                              \
      if (lrow >= 0) ga = *(const uint4*)(Ab + (size_t)lrow * 128 + kk);              \
      *(uint4*)&ldsA[buf][f * 512 + l * 8] = ga;                                      \
      *(uint4*)&ldsB[buf][f * 512 + l * 8] =                                          \
          *(const uint4*)(Wc + (size_t)(f * 16 + lr) * 384 + (ks) * 32 + lg * 8);     \
    }                                                                                 \
  }

  CSTAGE(0, 0)
  __syncthreads();
  for (int ks = 0; ks < 12; ++ks) {
    int buf = ks & 1;
    if (ks + 1 < 12) CSTAGE((ks + 1) & 1, ks + 1)
    short8v a[4], bq[4];
#pragma unroll
    for (int i = 0; i < 4; ++i)
      a[i] = *(const short8v*)&ldsA[buf][((wr >> 4) + i) * 512 + l * 8];
#pragma unroll
    for (int j = 0; j < 4; ++j)
      bq[j] = *(const short8v*)&ldsB[buf][((wcc >> 4) + j) * 512 + l * 8];
#pragma unroll
    for (int i = 0; i < 4; ++i)
#pragma unroll
      for (int j = 0; j < 4; ++j)
        acc[i][j] = __builtin_amdgcn_mfma_f32_16x16x32_bf16(a[i], bq[j], acc[i][j], 0, 0, 0);
    __syncthreads();
  }

  __hip_bfloat16* Ob = Out + (size_t)b * 32768;
#pragma unroll
  for (int i = 0; i < 4; ++i) {
#pragma unroll
    for (int j = 0; j < 4; ++j) {
      int r = trt * 128 + wr + i * 16 + lg * 4;  // l
      int c = wcc + j * 16 + lr;                 // o
      f32x4 v = acc[i][j];
      float bv = bias[c];
      uint2 p;
      p.x = pk2bf(v[0] + bv, v[1] + bv);
      p.y = pk2bf(v[2] + bv, v[3] + bv);
      *(uint2*)(Ob + (size_t)c * 256 + r) = p;
    }
  }
}

// ---------------- MFMA gram + row softmax ----------------
template <int N, int D>
__global__ __launch_bounds__(256) void gram_mfma(
    const __hip_bfloat16* __restrict__ X, const float* __restrict__ Wq,
    const float* __restrict__ Wk, __hip_bfloat16* __restrict__ P, float scale)
{
  constexpr int NT = N / 16;   // col tiles
  constexpr int KS = D / 32;   // k steps
  int b = blockIdx.y;
  int t = threadIdx.x, l = t & 63, w = t >> 6;
  int lr = l & 15, lg = l >> 4;
  int rowbase = blockIdx.x * 64 + w * 16;
  const __hip_bfloat16* Xb = X + (size_t)b * N * D;

  f32x4 acc[NT] = {};
#pragma unroll
  for (int ks = 0; ks < KS; ++ks) {
    short8v a = *(const short8v*)(Xb + (size_t)(rowbase + lr) * D + ks * 32 + lg * 8);
#pragma unroll
    for (int m = 0; m < NT; ++m) {
      short8v bb = *(const short8v*)(Xb + (size_t)(m * 16 + lr) * D + ks * 32 + lg * 8);
      acc[m] = __builtin_amdgcn_mfma_f32_16x16x32_bf16(a, bb, acc[m], 0, 0, 0);
    }
  }

  float dkr[NT];
#pragma unroll
  for (int m = 0; m < NT; ++m) dkr[m] = Wk[(size_t)(m * 16 + lr) * (N + 1)] * scale;

#pragma unroll
  for (int i = 0; i < 4; ++i) {
    int row = rowbase + lg * 4 + i;
    float dq = Wq[(size_t)row * (N + 1)];
    float v[NT];
    float mx = -3.0e38f;
#pragma unroll
    for (int m = 0; m < NT; ++m) {
      v[m] = acc[m][i] * dq * dkr[m];
      mx = fmaxf(mx, v[m]);
    }
#pragma unroll
    for (int off = 1; off < 16; off <<= 1) mx = fmaxf(mx, __shfl_xor(mx, off));
    float sum = 0.f;
#pragma unroll
    for (int m = 0; m < NT; ++m) { v[m] = __expf(v[m] - mx); sum += v[m]; }
#pragma unroll
    for (int off = 1; off < 16; off <<= 1) sum += __shfl_xor(sum, off);
    float inv = 1.0f / sum;
    __hip_bfloat16* Pr = P + (size_t)b * N * N + (size_t)row * N + lr;
#pragma unroll
    for (int m = 0; m < NT; ++m) Pr[m * 16] = __float2bfloat16(v[m] * inv);
  }
}

__global__ void reduceA(const __hip_bfloat16* __restrict__ P, float* __restrict__ A1,
                        float* __restrict__ A2, int N)
{
  int idx = blockIdx.x * 256 + threadIdx.x;
  size_t st = (size_t)N * N;
  const __hip_bfloat16* p = P + idx;
  float s = 0.f;
  for (int b = 0; b < NB; ++b) s += __bfloat162float(p[(size_t)b * st]);
  s *= (1.0f / NB);
  A1[idx] = s;
  A2[idx] = s;
}

__global__ void deg_dis(const float* __restrict__ A, float* __restrict__ dis, int N)
{
  int c = threadIdx.x;
  if (c < N) {
    float d = 0.f;
    for (int r = 0; r < N; ++r) d += A[r * N + c];
    dis[c] = (d > 0.f) ? (1.0f / sqrtf(d)) : 0.0f;
  }
}

// Bt_MT[n][n'] = dis[n]*dis[n']*A[n'][n]  (bf16, row-major)
__global__ void mt_bf16(const float* __restrict__ A, const float* __restrict__ dis,
                        __hip_bfloat16* __restrict__ MT, int N)
{
  int idx = blockIdx.x * 256 + threadIdx.x;
  int c = idx / N, r = idx - c * N;
  MT[idx] = __float2bfloat16(dis[c] * dis[r] * A[r * N + c]);
}

// Wt[h][k] = bf16(W[k][h])
__global__ void wt_cast(const float* __restrict__ W, __hip_bfloat16* __restrict__ Wt,
                        int K, int H)
{
  int idx = blockIdx.x * 256 + threadIdx.x;
  int h = idx / K, k = idx - h * K;
  Wt[idx] = __float2bfloat16(W[(size_t)k * H + h]);
}

// ---------------- MFMA GEMM: D = A * Bt^T, out = D^T row-major bf16 ----------------
__global__ __launch_bounds__(256) void gemm_mfma(
    const __hip_bfloat16* __restrict__ A, long sA,
    const __hip_bfloat16* __restrict__ Bt, long sBt,
    const float* __restrict__ bias,
    __hip_bfloat16* __restrict__ Out, long sOut,
    int R, int K, int C, int tilesC)
{
  __shared__ unsigned short ldsA[2][4096];
  __shared__ unsigned short ldsB[2][4096];
  int b = blockIdx.y;
  int tr = blockIdx.x / tilesC, tc = blockIdx.x - tr * tilesC;
  int t = threadIdx.x, l = t & 63, w = t >> 6;
  int wr = (w >> 1) * 64, wc = (w & 1) * 64;
  const __hip_bfloat16* Ab = A + (size_t)b * sA + (size_t)(tr * 128) * K;
  const __hip_bfloat16* Btb = Bt + (size_t)b * sBt + (size_t)(tc * 128) * K;

  f32x4 acc[4][4] = {};
  int lr = l & 15, lg = l >> 4;
  int nk = K >> 5;

#define STAGE(buf, ks)                                                              \
  {                                                                                 \
    int kk = (ks) * 32 + lg * 8;                                                    \
    _Pragma("unroll") for (int ff = 0; ff < 2; ++ff) {                              \
      int f = 2 * w + ff;                                                           \
      int row = f * 16 + lr;                                                        \
      *(uint4*)&ldsA[buf][f * 512 + l * 8] = *(const uint4*)(Ab + (size_t)row * K + kk); \
      *(uint4*)&ldsB[buf][f * 512 + l * 8] = *(const uint4*)(Btb + (size_t)row * K + kk);\
    }                                                                               \
  }

  STAGE(0, 0)
  __syncthreads();
  for (int ks = 0; ks < nk; ++ks) {
    int buf = ks & 1;
    if (ks + 1 < nk) STAGE((ks + 1) & 1, ks + 1)
    short8v a[4], bq[4];
#pragma unroll
    for (int i = 0; i < 4; ++i)
      a[i] = *(const short8v*)&ldsA[buf][((wr >> 4) + i) * 512 + l * 8];
#pragma unroll
    for (int j = 0; j < 4; ++j)
      bq[j] = *(const short8v*)&ldsB[buf][((wc >> 4) + j) * 512 + l * 8];
#pragma unroll
    for (int i = 0; i < 4; ++i)
#pragma unroll
      for (int j = 0; j < 4; ++j)
        acc[i][j] = __builtin_amdgcn_mfma_f32_16x16x32_bf16(a[i], bq[j], acc[i][j], 0, 0, 0);
    __syncthreads();
  }

  __hip_bfloat16* Ob = Out + (size_t)b * sOut;
#pragma unroll
  for (int i = 0; i < 4; ++i) {
#pragma unroll
    for (int j = 0; j < 4; ++j) {
      int r = tr * 128 + wr + i * 16 + lg * 4;
      int c = tc * 128 + wc + j * 16 + lr;
      f32x4 v = acc[i][j];
      if (bias) {
        v[0] += bias[r + 0];
        v[1] += bias[r + 1];
        v[2] += bias[r + 2];
        v[3] += bias[r + 3];
      }
      uint2 p;
      p.x = pk2bf(v[0], v[1]);
      p.y = pk2bf(v[2], v[3]);
      *(uint2*)(Ob + (size_t)c * R + r) = p;
    }
  }
}

// out[b][h] = mean_n H[b][n][h], H bf16 [N][128] rm
__global__ void mean_nodes(const __hip_bfloat16* __restrict__ Hb, float* __restrict__ out, int N)
{
  int b = blockIdx.x, h = threadIdx.x;
  const __hip_bfloat16* p = Hb + (size_t)b * N * 128 + h;
  float s = 0.f;
  for (int c = 0; c < N; ++c) s += __bfloat162float(p[c * 128]);
  out[b * 128 + h] = s * (1.0f / N);
}

__global__ void proj_kernel(const float* __restrict__ of, const float* __restrict__ ot,
                            const float* __restrict__ pw, const float* __restrict__ pb,
                            float* __restrict__ out)
{
  int idx = blockIdx.x * 256 + threadIdx.x;  // < 512*64
  int b = idx >> 6, o = idx & 63;
  float s = pb[o];
  const float* f = of + b * 128;
  const float* tt = ot + b * 128;
#pragma unroll 4
  for (int j = 0; j < 128; ++j) s += f[j] * pw[j * 64 + o];
#pragma unroll 4
  for (int j = 0; j < 128; ++j) s += tt[j] * pw[(128 + j) * 64 + o];
  out[idx] = s;
}

extern "C" void kernel_launch(void* const* d_in, const int* in_sizes, int n_in,
                              void* d_out, int out_size, void* d_ws, size_t ws_size,
                              hipStream_t stream)
{
  const float* X_time = (const float*)d_in[0];
  const float* conv_w = (const float*)d_in[1];
  const float* conv_b = (const float*)d_in[2];
  const float* wq_feat = (const float*)d_in[3];
  const float* wk_feat = (const float*)d_in[4];
  const float* wq_time = (const float*)d_in[5];
  const float* wk_time = (const float*)d_in[6];
  const float* gf1_w = (const float*)d_in[7];
  const float* gf1_b = (const float*)d_in[8];
  const float* gf2_w = (const float*)d_in[9];
  const float* gf2_b = (const float*)d_in[10];
  const float* gf3_w = (const float*)d_in[11];
  const float* gf3_b = (const float*)d_in[12];
  const float* gt1_w = (const float*)d_in[13];
  const float* gt1_b = (const float*)d_in[14];
  const float* gt2_w = (const float*)d_in[15];
  const float* gt2_b = (const float*)d_in[16];
  const float* gt3_w = (const float*)d_in[17];
  const float* gt3_b = (const float*)d_in[18];
  const float* proj_w = (const float*)d_in[19];
  const float* proj_b = (const float*)d_in[20];

  typedef __hip_bfloat16 bf16;
  char* ws = (char*)d_ws;
  const size_t MiB = 1ull << 20;
  // Layout (MiB): 0..32 XFb (later T0), 34..66 Xtb (later T1),
  //               68..132 Pt (later F0@68, F1@102), 136..152 Pf,
  //               153..185 Xt (conv only), 187+ smalls
  bf16* XFb = (bf16*)ws;
  bf16* Xtb = (bf16*)(ws + 34 * MiB);
  bf16* Pt = (bf16*)(ws + 68 * MiB);
  bf16* Pf = (bf16*)(ws + 136 * MiB);
  bf16* Xt = (bf16*)(ws + 153 * MiB);
  bf16* F0 = (bf16*)(ws + 68 * MiB);
  bf16* F1 = (bf16*)(ws + 102 * MiB);
  bf16* T0 = (bf16*)ws;
  bf16* T1 = (bf16*)(ws + 34 * MiB);
  char* SM = ws + 187 * MiB;
  float* A_feat = (float*)SM;
  float* A_time = (float*)(SM + 65536);
  float* dis_f = (float*)(SM + 327680);
  float* dis_t = (float*)(SM + 329728);
  bf16* MTf = (bf16*)(SM + 331776);
  bf16* MTt = (bf16*)(SM + 364544);
  bf16* w1f = (bf16*)(SM + 495616);
  bf16* w2f = (bf16*)(SM + 561152);
  bf16* w3f = (bf16*)(SM + 593920);
  bf16* w1t = (bf16*)(SM + 626688);
  bf16* w2t = (bf16*)(SM + 659456);
  bf16* w3t = (bf16*)(SM + 692224);
  bf16* Wcv = (bf16*)(SM + 724992 + 524288);  // conv Wc 96KB
  float* out_f = (float*)(SM + 724992);
  float* out_t = (float*)(SM + 987136);

  float* out = (float*)d_out;
  float* outA_f = out + 32768;
  float* outA_t = out + 49152;

  // 1) prep (bf16 flat + transpose) + conv via MFMA
  prep_x<<<NB, 256, 0, stream>>>(X_time, Xtb, Xt);
  wc_cast<<<192, 256, 0, stream>>>(conv_w, Wcv);
  conv_gemm<<<dim3(2, NB), 256, 0, stream>>>(Xt, Wcv, conv_b, XFb);
  // 2) MFMA grams + per-batch softmax
  gram_mfma<128, 256><<<dim3(2, NB), 256, 0, stream>>>(XFb, wq_feat, wk_feat, Pf, 0.0625f);
  gram_mfma<256, 128><<<dim3(4, NB), 256, 0, stream>>>(Xtb, wq_time, wk_time, Pt,
                                                       0.08838834764831845f);
  // 3) batch mean -> A (ws + d_out)
  reduceA<<<64, 256, 0, stream>>>(Pf, A_feat, outA_f, 128);
  reduceA<<<256, 256, 0, stream>>>(Pt, A_time, outA_t, 256);
  // 4) normalized adjacency + shared weight transposes
  deg_dis<<<1, 128, 0, stream>>>(A_feat, dis_f, 128);
  deg_dis<<<1, 256, 0, stream>>>(A_time, dis_t, 256);
  mt_bf16<<<64, 256, 0, stream>>>(A_feat, dis_f, MTf, 128);
  mt_bf16<<<256, 256, 0, stream>>>(A_time, dis_t, MTt, 256);
  wt_cast<<<128, 256, 0, stream>>>(gf1_w, w1f, 256, 128);
  wt_cast<<<64, 256, 0, stream>>>(gf2_w, w2f, 128, 128);
  wt_cast<<<64, 256, 0, stream>>>(gf3_w, w3f, 128, 128);
  wt_cast<<<64, 256, 0, stream>>>(gt1_w, w1t, 128, 128);
  wt_cast<<<64, 256, 0, stream>>>(gt2_w, w2t, 128, 128);
  wt_cast<<<64, 256, 0, stream>>>(gt3_w, w3t, 128, 128);

  // 5) feat GCN (N=128)
  gemm_mfma<<<dim3(1, NB), 256, 0, stream>>>(XFb, 32768, w1f, 0, nullptr, F0, 16384, 128, 256, 128, 1);
  gemm_mfma<<<dim3(1, NB), 256, 0, stream>>>(F0, 16384, MTf, 0, gf1_b, F1, 16384, 128, 128, 128, 1);
  gemm_mfma<<<dim3(1, NB), 256, 0, stream>>>(F1, 16384, w2f, 0, nullptr, F0, 16384, 128, 128, 128, 1);
  gemm_mfma<<<dim3(1, NB), 256, 0, stream>>>(F0, 16384, MTf, 0, gf2_b, F1, 16384, 128, 128, 128, 1);
  gemm_mfma<<<dim3(1, NB), 256, 0, stream>>>(F1, 16384, w3f, 0, nullptr, F0, 16384, 128, 128, 128, 1);
  gemm_mfma<<<dim3(1, NB), 256, 0, stream>>>(F0, 16384, MTf, 0, gf3_b, F1, 16384, 128, 128, 128, 1);
  mean_nodes<<<NB, 128, 0, stream>>>(F1, out_f, 128);

  // 6) time GCN (N=256)
  gemm_mfma<<<dim3(2, NB), 256, 0, stream>>>(Xtb, 32768, w1t, 0, nullptr, T0, 32768, 256, 128, 128, 1);
  gemm_mfma<<<dim3(2, NB), 256, 0, stream>>>(T0, 32768, MTt, 0, gt1_b, T1, 32768, 128, 256, 256, 2);
  gemm_mfma<<<dim3(2, NB), 256, 0, stream>>>(T1, 32768, w2t, 0, nullptr, T0, 32768, 256, 128, 128, 1);
  gemm_mfma<<<dim3(2, NB), 256, 0, stream>>>(T0, 32768, MTt, 0, gt2_b, T1, 32768, 128, 256, 256, 2);
  gemm_mfma<<<dim3(2, NB), 256, 0, stream>>>(T1, 32768, w3t, 0, nullptr, T0, 32768, 256, 128, 128, 1);
  gemm_mfma<<<dim3(2, NB), 256, 0, stream>>>(T0, 32768, MTt, 0, gt3_b, T1, 32768, 128, 256, 256, 2);
  mean_nodes<<<NB, 128, 0, stream>>>(T1, out_t, 256);

  // 7) projection
  proj_kernel<<<128, 256, 0, stream>>>(out_f, out_t, proj_w, proj_b, out);
}

// Round 6
// 734.516 us; speedup vs baseline: 2.8712x; 1.0106x over previous
//
#include <hip/hip_runtime.h>
#include <hip/hip_bf16.h>

#define NB 512
#define WD 256
#define NF 128

typedef __attribute__((ext_vector_type(8))) short short8v;
typedef __attribute__((ext_vector_type(4))) float f32x4;

__device__ inline unsigned pk2bf(float a, float b) {
  __hip_bfloat162 h;
  h.x = __float2bfloat16(a);
  h.y = __float2bfloat16(b);
  unsigned r;
  __builtin_memcpy(&r, &h, 4);
  return r;
}

// ---------------- prep: bf16 flat cast + bf16 transpose ----------------
__global__ __launch_bounds__(256) void prep_x(
    const float* __restrict__ X, __hip_bfloat16* __restrict__ Xflat,
    __hip_bfloat16* __restrict__ Xt)
{
  int b = blockIdx.x;
  const float* Xb = X + (size_t)b * 32768;
  __hip_bfloat16* Fb = Xflat + (size_t)b * 32768;
  __hip_bfloat16* Tb = Xt + (size_t)b * 32768;
  int t = threadIdx.x;
  for (int idx = t; idx < 8192; idx += 256) {
    float4 v = ((const float4*)Xb)[idx];
    uint2 p;
    p.x = pk2bf(v.x, v.y);
    p.y = pk2bf(v.z, v.w);
    ((uint2*)Fb)[idx] = p;
  }
  __shared__ float tile[32][33];
  int tr = t & 31, tc = t >> 5;  // 32 x 8
  for (int tt = 0; tt < 32; ++tt) {
    int r0 = (tt >> 3) * 32, c0 = (tt & 7) * 32;
    __syncthreads();
#pragma unroll
    for (int rr = tc; rr < 32; rr += 8)
      tile[rr][tr] = Xb[(size_t)(r0 + rr) * 256 + c0 + tr];
    __syncthreads();
#pragma unroll
    for (int rr = tc; rr < 32; rr += 8)
      Tb[(size_t)(c0 + rr) * 128 + r0 + tr] = __float2bfloat16(tile[tr][rr]);
  }
}

// Wc[o][k*128+i] = bf16(conv_w[o][i][k])  -- B^T operand of conv GEMM
__global__ void wc_cast(const float* __restrict__ W, __hip_bfloat16* __restrict__ Wc)
{
  int idx = blockIdx.x * 256 + threadIdx.x;  // 128*384
  int o = idx / 384, rem = idx - o * 384;
  int k = rem >> 7, i = rem & 127;
  Wc[idx] = __float2bfloat16(W[(size_t)o * 384 + i * 3 + k]);
}

// ---------------- conv as MFMA GEMM ----------------
__global__ __launch_bounds__(256) void conv_gemm(
    const __hip_bfloat16* __restrict__ Xt, const __hip_bfloat16* __restrict__ Wc,
    const float* __restrict__ bias, __hip_bfloat16* __restrict__ Out)
{
  __shared__ unsigned short ldsA[2][4096];
  __shared__ unsigned short ldsB[2][4096];
  int b = blockIdx.y;
  int trt = blockIdx.x;  // l-tile 0..1
  int t = threadIdx.x, l = t & 63, w = t >> 6;
  int wr = (w >> 1) * 64, wcc = (w & 1) * 64;
  int lr = l & 15, lg = l >> 4;
  const __hip_bfloat16* Ab = Xt + (size_t)b * 32768;
  f32x4 acc[4][4] = {};

#define CSTAGE(buf, ks)                                                               \
  {                                                                                   \
    int kgrp = (ks) >> 2;                                                             \
    int kk = ((ks) & 3) * 32 + lg * 8;                                                \
    _Pragma("unroll") for (int ff = 0; ff < 2; ++ff) {                                \
      int f = 2 * w + ff;                                                             \
      int lrow = trt * 128 + f * 16 + lr + 2 * kgrp - 4;                              \
      uint4 ga = make_uint4(0, 0, 0, 0);                                              \
      if (lrow >= 0) ga = *(const uint4*)(Ab + (size_t)lrow * 128 + kk);              \
      *(uint4*)&ldsA[buf][f * 512 + l * 8] = ga;                                      \
      *(uint4*)&ldsB[buf][f * 512 + l * 8] =                                          \
          *(const uint4*)(Wc + (size_t)(f * 16 + lr) * 384 + (ks) * 32 + lg * 8);     \
    }                                                                                 \
  }

  CSTAGE(0, 0)
  __syncthreads();
  for (int ks = 0; ks < 12; ++ks) {
    int buf = ks & 1;
    if (ks + 1 < 12) CSTAGE((ks + 1) & 1, ks + 1)
    short8v a[4], bq[4];
#pragma unroll
    for (int i = 0; i < 4; ++i)
      a[i] = *(const short8v*)&ldsA[buf][((wr >> 4) + i) * 512 + l * 8];
#pragma unroll
    for (int j = 0; j < 4; ++j)
      bq[j] = *(const short8v*)&ldsB[buf][((wcc >> 4) + j) * 512 + l * 8];
#pragma unroll
    for (int i = 0; i < 4; ++i)
#pragma unroll
      for (int j = 0; j < 4; ++j)
        acc[i][j] = __builtin_amdgcn_mfma_f32_16x16x32_bf16(a[i], bq[j], acc[i][j], 0, 0, 0);
    __syncthreads();
  }

  __hip_bfloat16* Ob = Out + (size_t)b * 32768;
#pragma unroll
  for (int i = 0; i < 4; ++i) {
#pragma unroll
    for (int j = 0; j < 4; ++j) {
      int r = trt * 128 + wr + i * 16 + lg * 4;  // l
      int c = wcc + j * 16 + lr;                 // o
      f32x4 v = acc[i][j];
      float bv = bias[c];
      uint2 p;
      p.x = pk2bf(v[0] + bv, v[1] + bv);
      p.y = pk2bf(v[2] + bv, v[3] + bv);
      *(uint2*)(Ob + (size_t)c * 256 + r) = p;
    }
  }
}

// ---------------- MFMA gram + row softmax (LDS-staged, XOR-swizzled) ----------------
// Full X_b (64KB bf16) staged once per block; byte ^= ((row&7)<<4) makes the
// 16-lane column-slice ds_read_b128 2-way (free) instead of 16-way (G4/T2).
template <int N, int D>
__global__ __launch_bounds__(256) void gram_mfma(
    const __hip_bfloat16* __restrict__ X, const float* __restrict__ Wq,
    const float* __restrict__ Wk, __hip_bfloat16* __restrict__ P, float scale)
{
  constexpr int NT = N / 16;   // col tiles
  constexpr int KS = D / 32;   // k steps
  constexpr int C8 = D / 8;    // 16B chunks per row
  __shared__ char lds[N * D * 2];  // 64KB
  int b = blockIdx.y;
  int t = threadIdx.x, l = t & 63, w = t >> 6;
  int lr = l & 15, lg = l >> 4;
  int rowbase = blockIdx.x * 64 + w * 16;
  const __hip_bfloat16* Xb = X + (size_t)b * N * D;

  // stage: row-major + XOR swizzle; coalesced global reads, conflict-free writes
  for (int chunk = t; chunk < N * C8; chunk += 256) {
    int row = chunk / C8, c8 = chunk - row * C8;
    int off = row * (2 * D) + ((c8 * 16) ^ ((row & 7) << 4));
    *(uint4*)(lds + off) = *(const uint4*)(Xb + (size_t)row * D + c8 * 8);
  }
  __syncthreads();

  int swz = (lr & 7) << 4;  // rowbase,m*16 are multiples of 16 -> row&7 == lr&7
  f32x4 acc[NT] = {};
#pragma unroll
  for (int ks = 0; ks < KS; ++ks) {
    int coff = (ks * 64 + lg * 16) ^ swz;
    short8v a = *(const short8v*)(lds + (rowbase + lr) * (2 * D) + coff);
#pragma unroll
    for (int m = 0; m < NT; ++m) {
      short8v bb = *(const short8v*)(lds + (m * 16 + lr) * (2 * D) + coff);
      acc[m] = __builtin_amdgcn_mfma_f32_16x16x32_bf16(a, bb, acc[m], 0, 0, 0);
    }
  }

  float dkr[NT];
#pragma unroll
  for (int m = 0; m < NT; ++m) dkr[m] = Wk[(size_t)(m * 16 + lr) * (N + 1)] * scale;

#pragma unroll
  for (int i = 0; i < 4; ++i) {
    int row = rowbase + lg * 4 + i;
    float dq = Wq[(size_t)row * (N + 1)];
    float v[NT];
    float mx = -3.0e38f;
#pragma unroll
    for (int m = 0; m < NT; ++m) {
      v[m] = acc[m][i] * dq * dkr[m];
      mx = fmaxf(mx, v[m]);
    }
#pragma unroll
    for (int off = 1; off < 16; off <<= 1) mx = fmaxf(mx, __shfl_xor(mx, off));
    float sum = 0.f;
#pragma unroll
    for (int m = 0; m < NT; ++m) { v[m] = __expf(v[m] - mx); sum += v[m]; }
#pragma unroll
    for (int off = 1; off < 16; off <<= 1) sum += __shfl_xor(sum, off);
    float inv = 1.0f / sum;
    __hip_bfloat16* Pr = P + (size_t)b * N * N + (size_t)row * N + lr;
#pragma unroll
    for (int m = 0; m < NT; ++m) Pr[m * 16] = __float2bfloat16(v[m] * inv);
  }
}

// A[n][m] = mean_b P[b][n][m]; 4 elems (uint2) per thread
__global__ void reduceA(const __hip_bfloat16* __restrict__ P, float* __restrict__ A1,
                        float* __restrict__ A2, int N)
{
  int idx = (blockIdx.x * 256 + threadIdx.x) * 4;
  size_t st = (size_t)N * N;
  const __hip_bfloat16* p = P + idx;
  float s0 = 0.f, s1 = 0.f, s2 = 0.f, s3 = 0.f;
#pragma unroll 4
  for (int b = 0; b < NB; ++b) {
    uint2 u = *(const uint2*)(p + (size_t)b * st);
    __hip_bfloat162 h0, h1;
    __builtin_memcpy(&h0, &u.x, 4);
    __builtin_memcpy(&h1, &u.y, 4);
    s0 += __bfloat162float(h0.x);
    s1 += __bfloat162float(h0.y);
    s2 += __bfloat162float(h1.x);
    s3 += __bfloat162float(h1.y);
  }
  float4 r = make_float4(s0 * (1.0f / NB), s1 * (1.0f / NB), s2 * (1.0f / NB), s3 * (1.0f / NB));
  *(float4*)(A1 + idx) = r;
  *(float4*)(A2 + idx) = r;
}

__global__ void deg_dis(const float* __restrict__ A, float* __restrict__ dis, int N)
{
  int c = threadIdx.x;
  if (c < N) {
    float d = 0.f;
    for (int r = 0; r < N; ++r) d += A[r * N + c];
    dis[c] = (d > 0.f) ? (1.0f / sqrtf(d)) : 0.0f;
  }
}

// Bt_MT[n][n'] = dis[n]*dis[n']*A[n'][n]  (bf16, row-major)
__global__ void mt_bf16(const float* __restrict__ A, const float* __restrict__ dis,
                        __hip_bfloat16* __restrict__ MT, int N)
{
  int idx = blockIdx.x * 256 + threadIdx.x;
  int c = idx / N, r = idx - c * N;
  MT[idx] = __float2bfloat16(dis[c] * dis[r] * A[r * N + c]);
}

// Wt[h][k] = bf16(W[k][h])
__global__ void wt_cast(const float* __restrict__ W, __hip_bfloat16* __restrict__ Wt,
                        int K, int H)
{
  int idx = blockIdx.x * 256 + threadIdx.x;
  int h = idx / K, k = idx - h * K;
  Wt[idx] = __float2bfloat16(W[(size_t)k * H + h]);
}

// ---------------- MFMA GEMM: D = A * Bt^T, out = D^T row-major bf16 ----------------
__global__ __launch_bounds__(256) void gemm_mfma(
    const __hip_bfloat16* __restrict__ A, long sA,
    const __hip_bfloat16* __restrict__ Bt, long sBt,
    const float* __restrict__ bias,
    __hip_bfloat16* __restrict__ Out, long sOut,
    int R, int K, int C, int tilesC)
{
  __shared__ unsigned short ldsA[2][4096];
  __shared__ unsigned short ldsB[2][4096];
  int b = blockIdx.y;
  int tr = blockIdx.x / tilesC, tc = blockIdx.x - tr * tilesC;
  int t = threadIdx.x, l = t & 63, w = t >> 6;
  int wr = (w >> 1) * 64, wc = (w & 1) * 64;
  const __hip_bfloat16* Ab = A + (size_t)b * sA + (size_t)(tr * 128) * K;
  const __hip_bfloat16* Btb = Bt + (size_t)b * sBt + (size_t)(tc * 128) * K;

  f32x4 acc[4][4] = {};
  int lr = l & 15, lg = l >> 4;
  int nk = K >> 5;

#define STAGE(buf, ks)                                                              \
  {                                                                                 \
    int kk = (ks) * 32 + lg * 8;                                                    \
    _Pragma("unroll") for (int ff = 0; ff < 2; ++ff) {                              \
      int f = 2 * w + ff;                                                           \
      int row = f * 16 + lr;                                                        \
      *(uint4*)&ldsA[buf][f * 512 + l * 8] = *(const uint4*)(Ab + (size_t)row * K + kk); \
      *(uint4*)&ldsB[buf][f * 512 + l * 8] = *(const uint4*)(Btb + (size_t)row * K + kk);\
    }                                                                               \
  }

  STAGE(0, 0)
  __syncthreads();
  for (int ks = 0; ks < nk; ++ks) {
    int buf = ks & 1;
    if (ks + 1 < nk) STAGE((ks + 1) & 1, ks + 1)
    short8v a[4], bq[4];
#pragma unroll
    for (int i = 0; i < 4; ++i)
      a[i] = *(const short8v*)&ldsA[buf][((wr >> 4) + i) * 512 + l * 8];
#pragma unroll
    for (int j = 0; j < 4; ++j)
      bq[j] = *(const short8v*)&ldsB[buf][((wc >> 4) + j) * 512 + l * 8];
#pragma unroll
    for (int i = 0; i < 4; ++i)
#pragma unroll
      for (int j = 0; j < 4; ++j)
        acc[i][j] = __builtin_amdgcn_mfma_f32_16x16x32_bf16(a[i], bq[j], acc[i][j], 0, 0, 0);
    __syncthreads();
  }

  __hip_bfloat16* Ob = Out + (size_t)b * sOut;
#pragma unroll
  for (int i = 0; i < 4; ++i) {
#pragma unroll
    for (int j = 0; j < 4; ++j) {
      int r = tr * 128 + wr + i * 16 + lg * 4;
      int c = tc * 128 + wc + j * 16 + lr;
      f32x4 v = acc[i][j];
      if (bias) {
        v[0] += bias[r + 0];
        v[1] += bias[r + 1];
        v[2] += bias[r + 2];
        v[3] += bias[r + 3];
      }
      uint2 p;
      p.x = pk2bf(v[0], v[1]);
      p.y = pk2bf(v[2], v[3]);
      *(uint2*)(Ob + (size_t)c * R + r) = p;
    }
  }
}

// out[b][h] = mean_n H[b][n][h], H bf16 [N][128] rm
__global__ void mean_nodes(const __hip_bfloat16* __restrict__ Hb, float* __restrict__ out, int N)
{
  int b = blockIdx.x, h = threadIdx.x;
  const __hip_bfloat16* p = Hb + (size_t)b * N * 128 + h;
  float s = 0.f;
  for (int c = 0; c < N; ++c) s += __bfloat162float(p[c * 128]);
  out[b * 128 + h] = s * (1.0f / N);
}

__global__ void proj_kernel(const float* __restrict__ of, const float* __restrict__ ot,
                            const float* __restrict__ pw, const float* __restrict__ pb,
                            float* __restrict__ out)
{
  int idx = blockIdx.x * 256 + threadIdx.x;  // < 512*64
  int b = idx >> 6, o = idx & 63;
  float s = pb[o];
  const float* f = of + b * 128;
  const float* tt = ot + b * 128;
#pragma unroll 4
  for (int j = 0; j < 128; ++j) s += f[j] * pw[j * 64 + o];
#pragma unroll 4
  for (int j = 0; j < 128; ++j) s += tt[j] * pw[(128 + j) * 64 + o];
  out[idx] = s;
}

extern "C" void kernel_launch(void* const* d_in, const int* in_sizes, int n_in,
                              void* d_out, int out_size, void* d_ws, size_t ws_size,
                              hipStream_t stream)
{
  const float* X_time = (const float*)d_in[0];
  const float* conv_w = (const float*)d_in[1];
  const float* conv_b = (const float*)d_in[2];
  const float* wq_feat = (const float*)d_in[3];
  const float* wk_feat = (const float*)d_in[4];
  const float* wq_time = (const float*)d_in[5];
  const float* wk_time = (const float*)d_in[6];
  const float* gf1_w = (const float*)d_in[7];
  const float* gf1_b = (const float*)d_in[8];
  const float* gf2_w = (const float*)d_in[9];
  const float* gf2_b = (const float*)d_in[10];
  const float* gf3_w = (const float*)d_in[11];
  const float* gf3_b = (const float*)d_in[12];
  const float* gt1_w = (const float*)d_in[13];
  const float* gt1_b = (const float*)d_in[14];
  const float* gt2_w = (const float*)d_in[15];
  const float* gt2_b = (const float*)d_in[16];
  const float* gt3_w = (const float*)d_in[17];
  const float* gt3_b = (const float*)d_in[18];
  const float* proj_w = (const float*)d_in[19];
  const float* proj_b = (const float*)d_in[20];

  typedef __hip_bfloat16 bf16;
  char* ws = (char*)d_ws;
  const size_t MiB = 1ull << 20;
  bf16* XFb = (bf16*)ws;
  bf16* Xtb = (bf16*)(ws + 34 * MiB);
  bf16* Pt = (bf16*)(ws + 68 * MiB);
  bf16* Pf = (bf16*)(ws + 136 * MiB);
  bf16* Xt = (bf16*)(ws + 153 * MiB);
  bf16* F0 = (bf16*)(ws + 68 * MiB);
  bf16* F1 = (bf16*)(ws + 102 * MiB);
  bf16* T0 = (bf16*)ws;
  bf16* T1 = (bf16*)(ws + 34 * MiB);
  char* SM = ws + 187 * MiB;
  float* A_feat = (float*)SM;
  float* A_time = (float*)(SM + 65536);
  float* dis_f = (float*)(SM + 327680);
  float* dis_t = (float*)(SM + 329728);
  bf16* MTf = (bf16*)(SM + 331776);
  bf16* MTt = (bf16*)(SM + 364544);
  bf16* w1f = (bf16*)(SM + 495616);
  bf16* w2f = (bf16*)(SM + 561152);
  bf16* w3f = (bf16*)(SM + 593920);
  bf16* w1t = (bf16*)(SM + 626688);
  bf16* w2t = (bf16*)(SM + 659456);
  bf16* w3t = (bf16*)(SM + 692224);
  bf16* Wcv = (bf16*)(SM + 724992 + 524288);
  float* out_f = (float*)(SM + 724992);
  float* out_t = (float*)(SM + 987136);

  float* out = (float*)d_out;
  float* outA_f = out + 32768;
  float* outA_t = out + 49152;

  // 1) prep (bf16 flat + transpose) + conv via MFMA
  prep_x<<<NB, 256, 0, stream>>>(X_time, Xtb, Xt);
  wc_cast<<<192, 256, 0, stream>>>(conv_w, Wcv);
  conv_gemm<<<dim3(2, NB), 256, 0, stream>>>(Xt, Wcv, conv_b, XFb);
  // 2) MFMA grams + per-batch softmax (LDS-staged)
  gram_mfma<128, 256><<<dim3(2, NB), 256, 0, stream>>>(XFb, wq_feat, wk_feat, Pf, 0.0625f);
  gram_mfma<256, 128><<<dim3(4, NB), 256, 0, stream>>>(Xtb, wq_time, wk_time, Pt,
                                                       0.08838834764831845f);
  // 3) batch mean -> A (ws + d_out)
  reduceA<<<16, 256, 0, stream>>>(Pf, A_feat, outA_f, 128);
  reduceA<<<64, 256, 0, stream>>>(Pt, A_time, outA_t, 256);
  // 4) normalized adjacency + shared weight transposes
  deg_dis<<<1, 128, 0, stream>>>(A_feat, dis_f, 128);
  deg_dis<<<1, 256, 0, stream>>>(A_time, dis_t, 256);
  mt_bf16<<<64, 256, 0, stream>>>(A_feat, dis_f, MTf, 128);
  mt_bf16<<<256, 256, 0, stream>>>(A_time, dis_t, MTt, 256);
  wt_cast<<<128, 256, 0, stream>>>(gf1_w, w1f, 256, 128);
  wt_cast<<<64, 256, 0, stream>>>(gf2_w, w2f, 128, 128);
  wt_cast<<<64, 256, 0, stream>>>(gf3_w, w3f, 128, 128);
  wt_cast<<<64, 256, 0, stream>>>(gt1_w, w1t, 128, 128);
  wt_cast<<<64, 256, 0, stream>>>(gt2_w, w2t, 128, 128);
  wt_cast<<<64, 256, 0, stream>>>(gt3_w, w3t, 128, 128);

  // 5) feat GCN (N=128)
  gemm_mfma<<<dim3(1, NB), 256, 0, stream>>>(XFb, 32768, w1f, 0, nullptr, F0, 16384, 128, 256, 128, 1);
  gemm_mfma<<<dim3(1, NB), 256, 0, stream>>>(F0, 16384, MTf, 0, gf1_b, F1, 16384, 128, 128, 128, 1);
  gemm_mfma<<<dim3(1, NB), 256, 0, stream>>>(F1, 16384, w2f, 0, nullptr, F0, 16384, 128, 128, 128, 1);
  gemm_mfma<<<dim3(1, NB), 256, 0, stream>>>(F0, 16384, MTf, 0, gf2_b, F1, 16384, 128, 128, 128, 1);
  gemm_mfma<<<dim3(1, NB), 256, 0, stream>>>(F1, 16384, w3f, 0, nullptr, F0, 16384, 128, 128, 128, 1);
  gemm_mfma<<<dim3(1, NB), 256, 0, stream>>>(F0, 16384, MTf, 0, gf3_b, F1, 16384, 128, 128, 128, 1);
  mean_nodes<<<NB, 128, 0, stream>>>(F1, out_f, 128);

  // 6) time GCN (N=256)
  gemm_mfma<<<dim3(2, NB), 256, 0, stream>>>(Xtb, 32768, w1t, 0, nullptr, T0, 32768, 256, 128, 128, 1);
  gemm_mfma<<<dim3(2, NB), 256, 0, stream>>>(T0, 32768, MTt, 0, gt1_b, T1, 32768, 128, 256, 256, 2);
  gemm_mfma<<<dim3(2, NB), 256, 0, stream>>>(T1, 32768, w2t, 0, nullptr, T0, 32768, 256, 128, 128, 1);
  gemm_mfma<<<dim3(2, NB), 256, 0, stream>>>(T0, 32768, MTt, 0, gt2_b, T1, 32768, 128, 256, 256, 2);
  gemm_mfma<<<dim3(2, NB), 256, 0, stream>>>(T1, 32768, w3t, 0, nullptr, T0, 32768, 256, 128, 128, 1);
  gemm_mfma<<<dim3(2, NB), 256, 0, stream>>>(T0, 32768, MTt, 0, gt3_b, T1, 32768, 128, 256, 256, 2);
  mean_nodes<<<NB, 128, 0, stream>>>(T1, out_t, 256);

  // 7) projection
  proj_kernel<<<128, 256, 0, stream>>>(out_f, out_t, proj_w, proj_b, out);
}

// Round 7
// 541.760 us; speedup vs baseline: 3.8928x; 1.3558x over previous
//
#include <hip/hip_runtime.h>
#include <hip/hip_bf16.h>

#define NB 512
#define WD 256
#define NF 128

typedef __attribute__((ext_vector_type(8))) short short8v;
typedef __attribute__((ext_vector_type(4))) float f32x4;

__device__ inline unsigned pk2bf(float a, float b) {
  __hip_bfloat162 h;
  h.x = __float2bfloat16(a);
  h.y = __float2bfloat16(b);
  unsigned r;
  __builtin_memcpy(&r, &h, 4);
  return r;
}

// ---------------- prep: read X f32 once -> flat bf16 + transposed bf16 ----------------
// grid (32, NB): 32x32 tile (i0 = (tt>>3)*32 of 128, l0 = (tt&7)*32 of 256).
__global__ __launch_bounds__(256) void prep_x(
    const float* __restrict__ X, __hip_bfloat16* __restrict__ Xflat,
    __hip_bfloat16* __restrict__ Xt)
{
  __shared__ float tile[32][33];
  int b = blockIdx.y, tt = blockIdx.x;
  int i0 = (tt >> 3) * 32, l0 = (tt & 7) * 32;
  const float* Xb = X + (size_t)b * 32768;
  __hip_bfloat16* Fb = Xflat + (size_t)b * 32768;
  __hip_bfloat16* Tb = Xt + (size_t)b * 32768;
  int t = threadIdx.x;
  {
    int r = t >> 3, c4 = t & 7;
    float4 v = *(const float4*)(Xb + (size_t)(i0 + r) * 256 + l0 + c4 * 4);
    uint2 p;
    p.x = pk2bf(v.x, v.y);
    p.y = pk2bf(v.z, v.w);
    *(uint2*)(Fb + (size_t)(i0 + r) * 256 + l0 + c4 * 4) = p;
    tile[r][c4 * 4 + 0] = v.x;
    tile[r][c4 * 4 + 1] = v.y;
    tile[r][c4 * 4 + 2] = v.z;
    tile[r][c4 * 4 + 3] = v.w;
  }
  __syncthreads();
  {
    int cr = t >> 3, ch = t & 7;
    float a0 = tile[ch * 4 + 0][cr];
    float a1 = tile[ch * 4 + 1][cr];
    float a2 = tile[ch * 4 + 2][cr];
    float a3 = tile[ch * 4 + 3][cr];
    uint2 q;
    q.x = pk2bf(a0, a1);
    q.y = pk2bf(a2, a3);
    *(uint2*)(Tb + (size_t)(l0 + cr) * 128 + i0 + ch * 4) = q;
  }
}

// Wc[o][k*128+i] = bf16(conv_w[o][i][k])  -- B^T operand of conv GEMM
__global__ void wc_cast(const float* __restrict__ W, __hip_bfloat16* __restrict__ Wc)
{
  int idx = blockIdx.x * 256 + threadIdx.x;  // 128*384
  int o = idx / 384, rem = idx - o * 384;
  int k = rem >> 7, i = rem & 127;
  Wc[idx] = __float2bfloat16(W[(size_t)o * 384 + i * 3 + k]);
}

// ---------------- conv as MFMA GEMM ----------------
__global__ __launch_bounds__(256) void conv_gemm(
    const __hip_bfloat16* __restrict__ Xt, const __hip_bfloat16* __restrict__ Wc,
    const float* __restrict__ bias, __hip_bfloat16* __restrict__ Out)
{
  __shared__ unsigned short ldsA[2][4096];
  __shared__ unsigned short ldsB[2][4096];
  int b = blockIdx.y;
  int trt = blockIdx.x;  // l-tile 0..1
  int t = threadIdx.x, l = t & 63, w = t >> 6;
  int wr = (w >> 1) * 64, wcc = (w & 1) * 64;
  int lr = l & 15, lg = l >> 4;
  const __hip_bfloat16* Ab = Xt + (size_t)b * 32768;
  f32x4 acc[4][4] = {};

#define CSTAGE(buf, ks)                                                               \
  {                                                                                   \
    int kgrp = (ks) >> 2;                                                             \
    int kk = ((ks) & 3) * 32 + lg * 8;                                                \
    _Pragma("unroll") for (int ff = 0; ff < 2; ++ff) {                                \
      int f = 2 * w + ff;                                                             \
      int lrow = trt * 128 + f * 16 + lr + 2 * kgrp - 4;                              \
      uint4 ga = make_uint4(0, 0, 0, 0);                                              \
      if (lrow >= 0) ga = *(const uint4*)(Ab + (size_t)lrow * 128 + kk);              \
      *(uint4*)&ldsA[buf][f * 512 + l * 8] = ga;                                      \
      *(uint4*)&ldsB[buf][f * 512 + l * 8] =                                          \
          *(const uint4*)(Wc + (size_t)(f * 16 + lr) * 384 + (ks) * 32 + lg * 8);     \
    }                                                                                 \
  }

  CSTAGE(0, 0)
  __syncthreads();
  for (int ks = 0; ks < 12; ++ks) {
    int buf = ks & 1;
    if (ks + 1 < 12) CSTAGE((ks + 1) & 1, ks + 1)
    short8v a[4], bq[4];
#pragma unroll
    for (int i = 0; i < 4; ++i)
      a[i] = *(const short8v*)&ldsA[buf][((wr >> 4) + i) * 512 + l * 8];
#pragma unroll
    for (int j = 0; j < 4; ++j)
      bq[j] = *(const short8v*)&ldsB[buf][((wcc >> 4) + j) * 512 + l * 8];
#pragma unroll
    for (int i = 0; i < 4; ++i)
#pragma unroll
      for (int j = 0; j < 4; ++j)
        acc[i][j] = __builtin_amdgcn_mfma_f32_16x16x32_bf16(a[i], bq[j], acc[i][j], 0, 0, 0);
    __syncthreads();
  }

  __hip_bfloat16* Ob = Out + (size_t)b * 32768;
#pragma unroll
  for (int i = 0; i < 4; ++i) {
#pragma unroll
    for (int j = 0; j < 4; ++j) {
      int r = trt * 128 + wr + i * 16 + lg * 4;  // l
      int c = wcc + j * 16 + lr;                 // o
      f32x4 v = acc[i][j];
      float bv = bias[c];
      uint2 p;
      p.x = pk2bf(v[0] + bv, v[1] + bv);
      p.y = pk2bf(v[2] + bv, v[3] + bv);
      *(uint2*)(Ob + (size_t)c * 256 + r) = p;
    }
  }
}

// ---------------- MFMA gram + row softmax (LDS-staged, XOR-swizzled) ----------------
template <int N, int D>
__global__ __launch_bounds__(256) void gram_mfma(
    const __hip_bfloat16* __restrict__ X, const float* __restrict__ Wq,
    const float* __restrict__ Wk, __hip_bfloat16* __restrict__ P, float scale)
{
  constexpr int NT = N / 16;   // col tiles
  constexpr int KS = D / 32;   // k steps
  constexpr int C8 = D / 8;    // 16B chunks per row
  __shared__ char lds[N * D * 2];  // 64KB
  int b = blockIdx.y;
  int t = threadIdx.x, l = t & 63, w = t >> 6;
  int lr = l & 15, lg = l >> 4;
  int rowbase = blockIdx.x * 64 + w * 16;
  const __hip_bfloat16* Xb = X + (size_t)b * N * D;

  for (int chunk = t; chunk < N * C8; chunk += 256) {
    int row = chunk / C8, c8 = chunk - row * C8;
    int off = row * (2 * D) + ((c8 * 16) ^ ((row & 7) << 4));
    *(uint4*)(lds + off) = *(const uint4*)(Xb + (size_t)row * D + c8 * 8);
  }
  __syncthreads();

  int swz = (lr & 7) << 4;
  f32x4 acc[NT] = {};
#pragma unroll
  for (int ks = 0; ks < KS; ++ks) {
    int coff = (ks * 64 + lg * 16) ^ swz;
    short8v a = *(const short8v*)(lds + (rowbase + lr) * (2 * D) + coff);
#pragma unroll
    for (int m = 0; m < NT; ++m) {
      short8v bb = *(const short8v*)(lds + (m * 16 + lr) * (2 * D) + coff);
      acc[m] = __builtin_amdgcn_mfma_f32_16x16x32_bf16(a, bb, acc[m], 0, 0, 0);
    }
  }

  float dkr[NT];
#pragma unroll
  for (int m = 0; m < NT; ++m) dkr[m] = Wk[(size_t)(m * 16 + lr) * (N + 1)] * scale;

#pragma unroll
  for (int i = 0; i < 4; ++i) {
    int row = rowbase + lg * 4 + i;
    float dq = Wq[(size_t)row * (N + 1)];
    float v[NT];
    float mx = -3.0e38f;
#pragma unroll
    for (int m = 0; m < NT; ++m) {
      v[m] = acc[m][i] * dq * dkr[m];
      mx = fmaxf(mx, v[m]);
    }
#pragma unroll
    for (int off = 1; off < 16; off <<= 1) mx = fmaxf(mx, __shfl_xor(mx, off));
    float sum = 0.f;
#pragma unroll
    for (int m = 0; m < NT; ++m) { v[m] = __expf(v[m] - mx); sum += v[m]; }
#pragma unroll
    for (int off = 1; off < 16; off <<= 1) sum += __shfl_xor(sum, off);
    float inv = 1.0f / sum;
    __hip_bfloat16* Pr = P + (size_t)b * N * N + (size_t)row * N + lr;
#pragma unroll
    for (int m = 0; m < NT; ++m) Pr[m * 16] = __float2bfloat16(v[m] * inv);
  }
}

// partial over 64-batch groups: partial[bg][idx..idx+3]
__global__ void reduceA_part(const __hip_bfloat16* __restrict__ P,
                             float* __restrict__ partial, int NN)
{
  int idx = (blockIdx.x * 256 + threadIdx.x) * 4;
  int bg = blockIdx.y;
  const __hip_bfloat16* p = P + (size_t)bg * 64 * NN + idx;
  float s0 = 0.f, s1 = 0.f, s2 = 0.f, s3 = 0.f;
#pragma unroll 4
  for (int b = 0; b < 64; ++b) {
    uint2 u = *(const uint2*)(p + (size_t)b * NN);
    __hip_bfloat162 h0, h1;
    __builtin_memcpy(&h0, &u.x, 4);
    __builtin_memcpy(&h1, &u.y, 4);
    s0 += __bfloat162float(h0.x);
    s1 += __bfloat162float(h0.y);
    s2 += __bfloat162float(h1.x);
    s3 += __bfloat162float(h1.y);
  }
  *(float4*)(partial + (size_t)bg * NN + idx) = make_float4(s0, s1, s2, s3);
}

__global__ void reduceA_fin(const float* __restrict__ partial, float* __restrict__ A1,
                            float* __restrict__ A2, int NN)
{
  int idx = (blockIdx.x * 256 + threadIdx.x) * 4;
  float4 a = make_float4(0.f, 0.f, 0.f, 0.f);
#pragma unroll
  for (int g = 0; g < 8; ++g) {
    float4 v = *(const float4*)(partial + (size_t)g * NN + idx);
    a.x += v.x; a.y += v.y; a.z += v.z; a.w += v.w;
  }
  a.x *= (1.0f / NB); a.y *= (1.0f / NB); a.z *= (1.0f / NB); a.w *= (1.0f / NB);
  *(float4*)(A1 + idx) = a;
  *(float4*)(A2 + idx) = a;
}

__global__ void deg_dis(const float* __restrict__ A, float* __restrict__ dis, int N)
{
  int c = threadIdx.x;
  if (c < N) {
    float d = 0.f;
    for (int r = 0; r < N; ++r) d += A[r * N + c];
    dis[c] = (d > 0.f) ? (1.0f / sqrtf(d)) : 0.0f;
  }
}

// Bt_MT[n][n'] = dis[n]*dis[n']*A[n'][n]  (bf16, row-major)
__global__ void mt_bf16(const float* __restrict__ A, const float* __restrict__ dis,
                        __hip_bfloat16* __restrict__ MT, int N)
{
  int idx = blockIdx.x * 256 + threadIdx.x;
  int c = idx / N, r = idx - c * N;
  MT[idx] = __float2bfloat16(dis[c] * dis[r] * A[r * N + c]);
}

// all 6 GCN weight transposes in one dispatch (Wt[h][k] = bf16(W[k][h]), H=128)
__global__ void wt_cast_all(
    const float* __restrict__ g1, const float* __restrict__ g2, const float* __restrict__ g3,
    const float* __restrict__ t1, const float* __restrict__ t2, const float* __restrict__ t3,
    __hip_bfloat16* __restrict__ o1, __hip_bfloat16* __restrict__ o2,
    __hip_bfloat16* __restrict__ o3, __hip_bfloat16* __restrict__ o4,
    __hip_bfloat16* __restrict__ o5, __hip_bfloat16* __restrict__ o6)
{
  int bid = blockIdx.x;
  const float* W;
  __hip_bfloat16* O;
  int K, idx;
  if (bid < 128) {
    W = g1; O = o1; K = 256; idx = bid * 256 + threadIdx.x;
  } else {
    int q = (bid - 128) >> 6, r2 = (bid - 128) & 63;
    K = 128; idx = r2 * 256 + threadIdx.x;
    switch (q) {
      case 0: W = g2; O = o2; break;
      case 1: W = g3; O = o3; break;
      case 2: W = t1; O = o4; break;
      case 3: W = t2; O = o5; break;
      default: W = t3; O = o6; break;
    }
  }
  int h = idx / K, k = idx - h * K;
  O[idx] = __float2bfloat16(W[(size_t)k * 128 + h]);
}

// ---------------- MFMA GEMM: D = A * Bt^T, out = D^T row-major bf16 ----------------
__global__ __launch_bounds__(256) void gemm_mfma(
    const __hip_bfloat16* __restrict__ A, long sA,
    const __hip_bfloat16* __restrict__ Bt, long sBt,
    const float* __restrict__ bias,
    __hip_bfloat16* __restrict__ Out, long sOut,
    int R, int K, int C, int tilesC)
{
  __shared__ unsigned short ldsA[2][4096];
  __shared__ unsigned short ldsB[2][4096];
  int b = blockIdx.y;
  int tr = blockIdx.x / tilesC, tc = blockIdx.x - tr * tilesC;
  int t = threadIdx.x, l = t & 63, w = t >> 6;
  int wr = (w >> 1) * 64, wc = (w & 1) * 64;
  const __hip_bfloat16* Ab = A + (size_t)b * sA + (size_t)(tr * 128) * K;
  const __hip_bfloat16* Btb = Bt + (size_t)b * sBt + (size_t)(tc * 128) * K;

  f32x4 acc[4][4] = {};
  int lr = l & 15, lg = l >> 4;
  int nk = K >> 5;

#define STAGE(buf, ks)                                                              \
  {                                                                                 \
    int kk = (ks) * 32 + lg * 8;                                                    \
    _Pragma("unroll") for (int ff = 0; ff < 2; ++ff) {                              \
      int f = 2 * w + ff;                                                           \
      int row = f * 16 + lr;                                                        \
      *(uint4*)&ldsA[buf][f * 512 + l * 8] = *(const uint4*)(Ab + (size_t)row * K + kk); \
      *(uint4*)&ldsB[buf][f * 512 + l * 8] = *(const uint4*)(Btb + (size_t)row * K + kk);\
    }                                                                               \
  }

  STAGE(0, 0)
  __syncthreads();
  for (int ks = 0; ks < nk; ++ks) {
    int buf = ks & 1;
    if (ks + 1 < nk) STAGE((ks + 1) & 1, ks + 1)
    short8v a[4], bq[4];
#pragma unroll
    for (int i = 0; i < 4; ++i)
      a[i] = *(const short8v*)&ldsA[buf][((wr >> 4) + i) * 512 + l * 8];
#pragma unroll
    for (int j = 0; j < 4; ++j)
      bq[j] = *(const short8v*)&ldsB[buf][((wc >> 4) + j) * 512 + l * 8];
#pragma unroll
    for (int i = 0; i < 4; ++i)
#pragma unroll
      for (int j = 0; j < 4; ++j)
        acc[i][j] = __builtin_amdgcn_mfma_f32_16x16x32_bf16(a[i], bq[j], acc[i][j], 0, 0, 0);
    __syncthreads();
  }

  __hip_bfloat16* Ob = Out + (size_t)b * sOut;
#pragma unroll
  for (int i = 0; i < 4; ++i) {
#pragma unroll
    for (int j = 0; j < 4; ++j) {
      int r = tr * 128 + wr + i * 16 + lg * 4;
      int c = tc * 128 + wc + j * 16 + lr;
      f32x4 v = acc[i][j];
      if (bias) {
        v[0] += bias[r + 0];
        v[1] += bias[r + 1];
        v[2] += bias[r + 2];
        v[3] += bias[r + 3];
      }
      uint2 p;
      p.x = pk2bf(v[0], v[1]);
      p.y = pk2bf(v[2], v[3]);
      *(uint2*)(Ob + (size_t)c * R + r) = p;
    }
  }
}

// out[b][h] = mean_c H[b][c][h]; uint4 loads + LDS reduce (G13)
__global__ __launch_bounds__(256) void mean_nodes(const __hip_bfloat16* __restrict__ H,
                                                  float* __restrict__ out, int N)
{
  __shared__ float red[16][128];
  int b = blockIdx.x, t = threadIdx.x;
  int rg = t >> 4, ch = t & 15;
  const __hip_bfloat16* Hb = H + (size_t)b * N * 128;
  float s[8] = {};
  for (int c = rg; c < N; c += 16) {
    uint4 u = *(const uint4*)(Hb + (size_t)c * 128 + ch * 8);
    unsigned arr[4] = {u.x, u.y, u.z, u.w};
#pragma unroll
    for (int q = 0; q < 4; ++q) {
      __hip_bfloat162 h2;
      __builtin_memcpy(&h2, &arr[q], 4);
      s[2 * q] += __bfloat162float(h2.x);
      s[2 * q + 1] += __bfloat162float(h2.y);
    }
  }
#pragma unroll
  for (int j = 0; j < 8; ++j) red[rg][ch * 8 + j] = s[j];
  __syncthreads();
  if (t < 128) {
    float tot = 0.f;
#pragma unroll
    for (int g = 0; g < 16; ++g) tot += red[g][t];
    out[b * 128 + t] = tot * (1.0f / N);
  }
}

__global__ void proj_kernel(const float* __restrict__ of, const float* __restrict__ ot,
                            const float* __restrict__ pw, const float* __restrict__ pb,
                            float* __restrict__ out)
{
  int idx = blockIdx.x * 256 + threadIdx.x;  // < 512*64
  int b = idx >> 6, o = idx & 63;
  float s = pb[o];
  const float* f = of + b * 128;
  const float* tt = ot + b * 128;
#pragma unroll 4
  for (int j = 0; j < 128; ++j) s += f[j] * pw[j * 64 + o];
#pragma unroll 4
  for (int j = 0; j < 128; ++j) s += tt[j] * pw[(128 + j) * 64 + o];
  out[idx] = s;
}

extern "C" void kernel_launch(void* const* d_in, const int* in_sizes, int n_in,
                              void* d_out, int out_size, void* d_ws, size_t ws_size,
                              hipStream_t stream)
{
  const float* X_time = (const float*)d_in[0];
  const float* conv_w = (const float*)d_in[1];
  const float* conv_b = (const float*)d_in[2];
  const float* wq_feat = (const float*)d_in[3];
  const float* wk_feat = (const float*)d_in[4];
  const float* wq_time = (const float*)d_in[5];
  const float* wk_time = (const float*)d_in[6];
  const float* gf1_w = (const float*)d_in[7];
  const float* gf1_b = (const float*)d_in[8];
  const float* gf2_w = (const float*)d_in[9];
  const float* gf2_b = (const float*)d_in[10];
  const float* gf3_w = (const float*)d_in[11];
  const float* gf3_b = (const float*)d_in[12];
  const float* gt1_w = (const float*)d_in[13];
  const float* gt1_b = (const float*)d_in[14];
  const float* gt2_w = (const float*)d_in[15];
  const float* gt2_b = (const float*)d_in[16];
  const float* gt3_w = (const float*)d_in[17];
  const float* gt3_b = (const float*)d_in[18];
  const float* proj_w = (const float*)d_in[19];
  const float* proj_b = (const float*)d_in[20];

  typedef __hip_bfloat16 bf16;
  char* ws = (char*)d_ws;
  const size_t MiB = 1ull << 20;
  bf16* XFb = (bf16*)ws;
  bf16* Xtb = (bf16*)(ws + 34 * MiB);
  bf16* Pt = (bf16*)(ws + 68 * MiB);
  bf16* Pf = (bf16*)(ws + 136 * MiB);
  bf16* Xt = (bf16*)(ws + 153 * MiB);
  bf16* F0 = (bf16*)(ws + 68 * MiB);
  bf16* F1 = (bf16*)(ws + 102 * MiB);
  bf16* T0 = (bf16*)ws;
  bf16* T1 = (bf16*)(ws + 34 * MiB);
  char* SM = ws + 187 * MiB;
  float* A_feat = (float*)SM;
  float* A_time = (float*)(SM + 65536);
  float* dis_f = (float*)(SM + 327680);
  float* dis_t = (float*)(SM + 329728);
  bf16* MTf = (bf16*)(SM + 331776);
  bf16* MTt = (bf16*)(SM + 364544);
  bf16* w1f = (bf16*)(SM + 495616);
  bf16* w2f = (bf16*)(SM + 561152);
  bf16* w3f = (bf16*)(SM + 593920);
  bf16* w1t = (bf16*)(SM + 626688);
  bf16* w2t = (bf16*)(SM + 659456);
  bf16* w3t = (bf16*)(SM + 692224);
  bf16* Wcv = (bf16*)(SM + 1249280);
  float* out_f = (float*)(SM + 724992);
  float* out_t = (float*)(SM + 987136);
  float* Pf_part = (float*)(SM + 2 * MiB);            // 512KB
  float* Pt_part = (float*)(SM + 2 * MiB + 524288);   // 2MB

  float* out = (float*)d_out;
  float* outA_f = out + 32768;
  float* outA_t = out + 49152;

  // 1) prep (flat bf16 + transposed bf16, one X read) + conv via MFMA
  prep_x<<<dim3(32, NB), 256, 0, stream>>>(X_time, Xtb, Xt);
  wc_cast<<<192, 256, 0, stream>>>(conv_w, Wcv);
  conv_gemm<<<dim3(2, NB), 256, 0, stream>>>(Xt, Wcv, conv_b, XFb);
  // 2) MFMA grams + per-batch softmax (LDS-staged)
  gram_mfma<128, 256><<<dim3(2, NB), 256, 0, stream>>>(XFb, wq_feat, wk_feat, Pf, 0.0625f);
  gram_mfma<256, 128><<<dim3(4, NB), 256, 0, stream>>>(Xtb, wq_time, wk_time, Pt,
                                                       0.08838834764831845f);
  // 3) batch mean -> A (8-way partials, then final)
  reduceA_part<<<dim3(16, 8), 256, 0, stream>>>(Pf, Pf_part, 16384);
  reduceA_part<<<dim3(64, 8), 256, 0, stream>>>(Pt, Pt_part, 65536);
  reduceA_fin<<<16, 256, 0, stream>>>(Pf_part, A_feat, outA_f, 16384);
  reduceA_fin<<<64, 256, 0, stream>>>(Pt_part, A_time, outA_t, 65536);
  // 4) normalized adjacency + shared weight transposes
  deg_dis<<<1, 128, 0, stream>>>(A_feat, dis_f, 128);
  deg_dis<<<1, 256, 0, stream>>>(A_time, dis_t, 256);
  mt_bf16<<<64, 256, 0, stream>>>(A_feat, dis_f, MTf, 128);
  mt_bf16<<<256, 256, 0, stream>>>(A_time, dis_t, MTt, 256);
  wt_cast_all<<<448, 256, 0, stream>>>(gf1_w, gf2_w, gf3_w, gt1_w, gt2_w, gt3_w,
                                       w1f, w2f, w3f, w1t, w2t, w3t);

  // 5) feat GCN (N=128)
  gemm_mfma<<<dim3(1, NB), 256, 0, stream>>>(XFb, 32768, w1f, 0, nullptr, F0, 16384, 128, 256, 128, 1);
  gemm_mfma<<<dim3(1, NB), 256, 0, stream>>>(F0, 16384, MTf, 0, gf1_b, F1, 16384, 128, 128, 128, 1);
  gemm_mfma<<<dim3(1, NB), 256, 0, stream>>>(F1, 16384, w2f, 0, nullptr, F0, 16384, 128, 128, 128, 1);
  gemm_mfma<<<dim3(1, NB), 256, 0, stream>>>(F0, 16384, MTf, 0, gf2_b, F1, 16384, 128, 128, 128, 1);
  gemm_mfma<<<dim3(1, NB), 256, 0, stream>>>(F1, 16384, w3f, 0, nullptr, F0, 16384, 128, 128, 128, 1);
  gemm_mfma<<<dim3(1, NB), 256, 0, stream>>>(F0, 16384, MTf, 0, gf3_b, F1, 16384, 128, 128, 128, 1);
  mean_nodes<<<NB, 256, 0, stream>>>(F1, out_f, 128);

  // 6) time GCN (N=256)
  gemm_mfma<<<dim3(2, NB), 256, 0, stream>>>(Xtb, 32768, w1t, 0, nullptr, T0, 32768, 256, 128, 128, 1);
  gemm_mfma<<<dim3(2, NB), 256, 0, stream>>>(T0, 32768, MTt, 0, gt1_b, T1, 32768, 128, 256, 256, 2);
  gemm_mfma<<<dim3(2, NB), 256, 0, stream>>>(T1, 32768, w2t, 0, nullptr, T0, 32768, 256, 128, 128, 1);
  gemm_mfma<<<dim3(2, NB), 256, 0, stream>>>(T0, 32768, MTt, 0, gt2_b, T1, 32768, 128, 256, 256, 2);
  gemm_mfma<<<dim3(2, NB), 256, 0, stream>>>(T1, 32768, w3t, 0, nullptr, T0, 32768, 256, 128, 128, 1);
  gemm_mfma<<<dim3(2, NB), 256, 0, stream>>>(T0, 32768, MTt, 0, gt3_b, T1, 32768, 128, 256, 256, 2);
  mean_nodes<<<NB, 256, 0, stream>>>(T1, out_t, 256);

  // 7) projection
  proj_kernel<<<128, 256, 0, stream>>>(out_f, out_t, proj_w, proj_b, out);
}

// Round 8
// 418.861 us; speedup vs baseline: 5.0350x; 1.2934x over previous
//
#include <hip/hip_runtime.h>
#include <hip/hip_bf16.h>

#define NB 512
#define WD 256
#define NF 128

typedef __attribute__((ext_vector_type(8))) short short8v;
typedef __attribute__((ext_vector_type(4))) float f32x4;

__device__ inline unsigned pk2bf(float a, float b) {
  __hip_bfloat162 h;
  h.x = __float2bfloat16(a);
  h.y = __float2bfloat16(b);
  unsigned r;
  __builtin_memcpy(&r, &h, 4);
  return r;
}

// ---------------- prep: read X f32 once -> flat bf16 + transposed bf16 ----------------
__global__ __launch_bounds__(256) void prep_x(
    const float* __restrict__ X, __hip_bfloat16* __restrict__ Xflat,
    __hip_bfloat16* __restrict__ Xt)
{
  __shared__ float tile[32][33];
  int b = blockIdx.y, tt = blockIdx.x;
  int i0 = (tt >> 3) * 32, l0 = (tt & 7) * 32;
  const float* Xb = X + (size_t)b * 32768;
  __hip_bfloat16* Fb = Xflat + (size_t)b * 32768;
  __hip_bfloat16* Tb = Xt + (size_t)b * 32768;
  int t = threadIdx.x;
  {
    int r = t >> 3, c4 = t & 7;
    float4 v = *(const float4*)(Xb + (size_t)(i0 + r) * 256 + l0 + c4 * 4);
    uint2 p;
    p.x = pk2bf(v.x, v.y);
    p.y = pk2bf(v.z, v.w);
    *(uint2*)(Fb + (size_t)(i0 + r) * 256 + l0 + c4 * 4) = p;
    tile[r][c4 * 4 + 0] = v.x;
    tile[r][c4 * 4 + 1] = v.y;
    tile[r][c4 * 4 + 2] = v.z;
    tile[r][c4 * 4 + 3] = v.w;
  }
  __syncthreads();
  {
    int cr = t >> 3, ch = t & 7;
    float a0 = tile[ch * 4 + 0][cr];
    float a1 = tile[ch * 4 + 1][cr];
    float a2 = tile[ch * 4 + 2][cr];
    float a3 = tile[ch * 4 + 3][cr];
    uint2 q;
    q.x = pk2bf(a0, a1);
    q.y = pk2bf(a2, a3);
    *(uint2*)(Tb + (size_t)(l0 + cr) * 128 + i0 + ch * 4) = q;
  }
}

// Wc[o][k*128+i] = bf16(conv_w[o][i][k])
__global__ void wc_cast(const float* __restrict__ W, __hip_bfloat16* __restrict__ Wc)
{
  int idx = blockIdx.x * 256 + threadIdx.x;  // 128*384
  int o = idx / 384, rem = idx - o * 384;
  int k = rem >> 7, i = rem & 127;
  Wc[idx] = __float2bfloat16(W[(size_t)o * 384 + i * 3 + k]);
}

// ---------------- conv as MFMA GEMM ----------------
__global__ __launch_bounds__(256) void conv_gemm(
    const __hip_bfloat16* __restrict__ Xt, const __hip_bfloat16* __restrict__ Wc,
    const float* __restrict__ bias, __hip_bfloat16* __restrict__ Out)
{
  __shared__ unsigned short ldsA[2][4096];
  __shared__ unsigned short ldsB[2][4096];
  int b = blockIdx.y;
  int trt = blockIdx.x;  // l-tile 0..1
  int t = threadIdx.x, l = t & 63, w = t >> 6;
  int wr = (w >> 1) * 64, wcc = (w & 1) * 64;
  int lr = l & 15, lg = l >> 4;
  const __hip_bfloat16* Ab = Xt + (size_t)b * 32768;
  f32x4 acc[4][4] = {};

#define CSTAGE(buf, ks)                                                               \
  {                                                                                   \
    int kgrp = (ks) >> 2;                                                             \
    int kk = ((ks) & 3) * 32 + lg * 8;                                                \
    _Pragma("unroll") for (int ff = 0; ff < 2; ++ff) {                                \
      int f = 2 * w + ff;                                                             \
      int lrow = trt * 128 + f * 16 + lr + 2 * kgrp - 4;                              \
      uint4 ga = make_uint4(0, 0, 0, 0);                                              \
      if (lrow >= 0) ga = *(const uint4*)(Ab + (size_t)lrow * 128 + kk);              \
      *(uint4*)&ldsA[buf][f * 512 + l * 8] = ga;                                      \
      *(uint4*)&ldsB[buf][f * 512 + l * 8] =                                          \
          *(const uint4*)(Wc + (size_t)(f * 16 + lr) * 384 + (ks) * 32 + lg * 8);     \
    }                                                                                 \
  }

  CSTAGE(0, 0)
  __syncthreads();
  for (int ks = 0; ks < 12; ++ks) {
    int buf = ks & 1;
    if (ks + 1 < 12) CSTAGE((ks + 1) & 1, ks + 1)
    short8v a[4], bq[4];
#pragma unroll
    for (int i = 0; i < 4; ++i)
      a[i] = *(const short8v*)&ldsA[buf][((wr >> 4) + i) * 512 + l * 8];
#pragma unroll
    for (int j = 0; j < 4; ++j)
      bq[j] = *(const short8v*)&ldsB[buf][((wcc >> 4) + j) * 512 + l * 8];
#pragma unroll
    for (int i = 0; i < 4; ++i)
#pragma unroll
      for (int j = 0; j < 4; ++j)
        acc[i][j] = __builtin_amdgcn_mfma_f32_16x16x32_bf16(a[i], bq[j], acc[i][j], 0, 0, 0);
    __syncthreads();
  }

  __hip_bfloat16* Ob = Out + (size_t)b * 32768;
#pragma unroll
  for (int i = 0; i < 4; ++i) {
#pragma unroll
    for (int j = 0; j < 4; ++j) {
      int r = trt * 128 + wr + i * 16 + lg * 4;  // l
      int c = wcc + j * 16 + lr;                 // o
      f32x4 v = acc[i][j];
      float bv = bias[c];
      uint2 p;
      p.x = pk2bf(v[0] + bv, v[1] + bv);
      p.y = pk2bf(v[2] + bv, v[3] + bv);
      *(uint2*)(Ob + (size_t)c * 256 + r) = p;
    }
  }
}

// ---------------- MFMA gram + row softmax (LDS-staged, XOR-swizzled) ----------------
template <int N, int D>
__global__ __launch_bounds__(256) void gram_mfma(
    const __hip_bfloat16* __restrict__ X, const float* __restrict__ Wq,
    const float* __restrict__ Wk, __hip_bfloat16* __restrict__ P, float scale)
{
  constexpr int NT = N / 16;
  constexpr int KS = D / 32;
  constexpr int C8 = D / 8;
  __shared__ char lds[N * D * 2];  // 64KB
  int b = blockIdx.y;
  int t = threadIdx.x, l = t & 63, w = t >> 6;
  int lr = l & 15, lg = l >> 4;
  int rowbase = blockIdx.x * 64 + w * 16;
  const __hip_bfloat16* Xb = X + (size_t)b * N * D;

  for (int chunk = t; chunk < N * C8; chunk += 256) {
    int row = chunk / C8, c8 = chunk - row * C8;
    int off = row * (2 * D) + ((c8 * 16) ^ ((row & 7) << 4));
    *(uint4*)(lds + off) = *(const uint4*)(Xb + (size_t)row * D + c8 * 8);
  }
  __syncthreads();

  int swz = (lr & 7) << 4;
  f32x4 acc[NT] = {};
#pragma unroll
  for (int ks = 0; ks < KS; ++ks) {
    int coff = (ks * 64 + lg * 16) ^ swz;
    short8v a = *(const short8v*)(lds + (rowbase + lr) * (2 * D) + coff);
#pragma unroll
    for (int m = 0; m < NT; ++m) {
      short8v bb = *(const short8v*)(lds + (m * 16 + lr) * (2 * D) + coff);
      acc[m] = __builtin_amdgcn_mfma_f32_16x16x32_bf16(a, bb, acc[m], 0, 0, 0);
    }
  }

  float dkr[NT];
#pragma unroll
  for (int m = 0; m < NT; ++m) dkr[m] = Wk[(size_t)(m * 16 + lr) * (N + 1)] * scale;

#pragma unroll
  for (int i = 0; i < 4; ++i) {
    int row = rowbase + lg * 4 + i;
    float dq = Wq[(size_t)row * (N + 1)];
    float v[NT];
    float mx = -3.0e38f;
#pragma unroll
    for (int m = 0; m < NT; ++m) {
      v[m] = acc[m][i] * dq * dkr[m];
      mx = fmaxf(mx, v[m]);
    }
#pragma unroll
    for (int off = 1; off < 16; off <<= 1) mx = fmaxf(mx, __shfl_xor(mx, off));
    float sum = 0.f;
#pragma unroll
    for (int m = 0; m < NT; ++m) { v[m] = __expf(v[m] - mx); sum += v[m]; }
#pragma unroll
    for (int off = 1; off < 16; off <<= 1) sum += __shfl_xor(sum, off);
    float inv = 1.0f / sum;
    __hip_bfloat16* Pr = P + (size_t)b * N * N + (size_t)row * N + lr;
#pragma unroll
    for (int m = 0; m < NT; ++m) Pr[m * 16] = __float2bfloat16(v[m] * inv);
  }
}

// partial over 64-batch groups
__global__ void reduceA_part(const __hip_bfloat16* __restrict__ P,
                             float* __restrict__ partial, int NN)
{
  int idx = (blockIdx.x * 256 + threadIdx.x) * 4;
  int bg = blockIdx.y;
  const __hip_bfloat16* p = P + (size_t)bg * 64 * NN + idx;
  float s0 = 0.f, s1 = 0.f, s2 = 0.f, s3 = 0.f;
#pragma unroll 4
  for (int b = 0; b < 64; ++b) {
    uint2 u = *(const uint2*)(p + (size_t)b * NN);
    __hip_bfloat162 h0, h1;
    __builtin_memcpy(&h0, &u.x, 4);
    __builtin_memcpy(&h1, &u.y, 4);
    s0 += __bfloat162float(h0.x);
    s1 += __bfloat162float(h0.y);
    s2 += __bfloat162float(h1.x);
    s3 += __bfloat162float(h1.y);
  }
  *(float4*)(partial + (size_t)bg * NN + idx) = make_float4(s0, s1, s2, s3);
}

__global__ void reduceA_fin(const float* __restrict__ partial, float* __restrict__ A1,
                            float* __restrict__ A2, int NN)
{
  int idx = (blockIdx.x * 256 + threadIdx.x) * 4;
  float4 a = make_float4(0.f, 0.f, 0.f, 0.f);
#pragma unroll
  for (int g = 0; g < 8; ++g) {
    float4 v = *(const float4*)(partial + (size_t)g * NN + idx);
    a.x += v.x; a.y += v.y; a.z += v.z; a.w += v.w;
  }
  a.x *= (1.0f / NB); a.y *= (1.0f / NB); a.z *= (1.0f / NB); a.w *= (1.0f / NB);
  *(float4*)(A1 + idx) = a;
  *(float4*)(A2 + idx) = a;
}

// parallel column-sum: dis[c] = deg[c]>0 ? 1/sqrt(deg[c]) : 0  (grid N/64, 256 thr)
__global__ __launch_bounds__(256) void deg_sum(const float* __restrict__ A,
                                               float* __restrict__ dis, int N)
{
  __shared__ float red[4][64];
  int t = threadIdx.x;
  int c = blockIdx.x * 64 + (t & 63);
  int rg = t >> 6;
  float s = 0.f;
  for (int r = rg; r < N; r += 4) s += A[(size_t)r * N + c];
  red[rg][t & 63] = s;
  __syncthreads();
  if (t < 64) {
    float d = red[0][t] + red[1][t] + red[2][t] + red[3][t];
    dis[blockIdx.x * 64 + t] = (d > 0.f) ? (1.0f / sqrtf(d)) : 0.0f;
  }
}

// Bt_MT[n][n'] = dis[n]*dis[n']*A[n'][n]
__global__ void mt_bf16(const float* __restrict__ A, const float* __restrict__ dis,
                        __hip_bfloat16* __restrict__ MT, int N)
{
  int idx = blockIdx.x * 256 + threadIdx.x;
  int c = idx / N, r = idx - c * N;
  MT[idx] = __float2bfloat16(dis[c] * dis[r] * A[r * N + c]);
}

// all 6 GCN weight transposes in one dispatch
__global__ void wt_cast_all(
    const float* __restrict__ g1, const float* __restrict__ g2, const float* __restrict__ g3,
    const float* __restrict__ t1, const float* __restrict__ t2, const float* __restrict__ t3,
    __hip_bfloat16* __restrict__ o1, __hip_bfloat16* __restrict__ o2,
    __hip_bfloat16* __restrict__ o3, __hip_bfloat16* __restrict__ o4,
    __hip_bfloat16* __restrict__ o5, __hip_bfloat16* __restrict__ o6)
{
  int bid = blockIdx.x;
  const float* W;
  __hip_bfloat16* O;
  int K, idx;
  if (bid < 128) {
    W = g1; O = o1; K = 256; idx = bid * 256 + threadIdx.x;
  } else {
    int q = (bid - 128) >> 6, r2 = (bid - 128) & 63;
    K = 128; idx = r2 * 256 + threadIdx.x;
    switch (q) {
      case 0: W = g2; O = o2; break;
      case 1: W = g3; O = o3; break;
      case 2: W = t1; O = o4; break;
      case 3: W = t2; O = o5; break;
      default: W = t3; O = o6; break;
    }
  }
  int h = idx / K, k = idx - h * K;
  O[idx] = __float2bfloat16(W[(size_t)k * 128 + h]);
}

// ---------------- fused GCN layer: OUT = M * (IN x W) + bias, per-batch block --------
// gemm1: T[n][h] = sum_k IN[n][k] Wt[h][k]; Tᵀ kept in LDS (fragment-granule layout).
// gemm2: D2'[h][n'] = sum_n Tᵀ[h][n] MT[n'][n]; transposing epilogue -> OUT[n'][h] rm.
// ldsT idx(h,n) = (h>>4)*16*N + (n>>3)*128 + (h&15)*8 + (n&7)   (shorts)
template <int N>
__global__ __launch_bounds__(256) void gcn_layer(
    const __hip_bfloat16* __restrict__ IN, int K1,
    const __hip_bfloat16* __restrict__ Wt,   // [128][K1]
    const __hip_bfloat16* __restrict__ MT,   // [N][N]: row n', k n
    const float* __restrict__ bias,          // [128]
    __hip_bfloat16* __restrict__ OUT)        // [N][128] per batch
{
  constexpr int NJ = N / 32;
  constexpr int NFRAG = N / 16;
  __shared__ unsigned short ldsT[128 * N];   // 32/64 KB
  __shared__ unsigned short stg[8192];       // 16 KB staging (A:0..4095, B:4096..)
  int b = blockIdx.x;
  int t = threadIdx.x, l = t & 63, w = t >> 6;
  int lr = l & 15, lg = l >> 4;
  int wr = (w >> 1) * 64, wc = (w & 1) * 64;
  const __hip_bfloat16* Ib = IN + (size_t)b * N * K1;
  int nk1 = K1 >> 5;

  // ---- gemm1: T = IN x W  -> ldsT (as Tᵀ) ----
  for (int rt = 0; rt < N / 128; ++rt) {
    f32x4 acc[4][4] = {};
    for (int ks = 0; ks < nk1; ++ks) {
      if (ks | rt) __syncthreads();
      {
        int kk = ks * 32 + lg * 8;
#pragma unroll
        for (int ff = 0; ff < 2; ++ff) {
          int f = 2 * w + ff;
          *(uint4*)&stg[f * 512 + l * 8] =
              *(const uint4*)(Ib + (size_t)(rt * 128 + f * 16 + lr) * K1 + kk);
          *(uint4*)&stg[4096 + f * 512 + l * 8] =
              *(const uint4*)(Wt + (size_t)(f * 16 + lr) * K1 + kk);
        }
      }
      __syncthreads();
      short8v a[4], bq[4];
#pragma unroll
      for (int i = 0; i < 4; ++i)
        a[i] = *(const short8v*)&stg[((wr >> 4) + i) * 512 + l * 8];
#pragma unroll
      for (int j = 0; j < 4; ++j)
        bq[j] = *(const short8v*)&stg[4096 + ((wc >> 4) + j) * 512 + l * 8];
#pragma unroll
      for (int i = 0; i < 4; ++i)
#pragma unroll
        for (int j = 0; j < 4; ++j)
          acc[i][j] = __builtin_amdgcn_mfma_f32_16x16x32_bf16(a[i], bq[j], acc[i][j], 0, 0, 0);
    }
    // epilogue -> ldsT (Tᵀ granules); n packed 4-wide
#pragma unroll
    for (int i = 0; i < 4; ++i) {
#pragma unroll
      for (int j = 0; j < 4; ++j) {
        int n0 = rt * 128 + wr + i * 16 + lg * 4;
        int h = wc + j * 16 + lr;
        int idx = (h >> 4) * (16 * N) + (n0 >> 3) * 128 + (h & 15) * 8 + (n0 & 7);
        f32x4 v = acc[i][j];
        uint2 p;
        p.x = pk2bf(v[0], v[1]);
        p.y = pk2bf(v[2], v[3]);
        *(uint2*)&ldsT[idx] = p;
      }
    }
  }
  __syncthreads();  // ldsT complete

  // ---- gemm2: D2' = Tᵀ x MTᵀ ----
  f32x4 acc2[4][NJ] = {};
  for (int ks = 0; ks < N / 32; ++ks) {
    if (ks) __syncthreads();
    {
      int kk = ks * 32 + lg * 8;
#pragma unroll
      for (int ff = 0; ff < NFRAG / 4; ++ff) {
        int f = (NFRAG / 4) * w + ff;
        *(uint4*)&stg[f * 512 + l * 8] =
            *(const uint4*)(MT + (size_t)(f * 16 + lr) * N + kk);
      }
    }
    __syncthreads();
    short8v a[4];
#pragma unroll
    for (int i = 0; i < 4; ++i)
      a[i] = *(const short8v*)&ldsT[((wr >> 4) + i) * (16 * N) + (ks * 4 + lg) * 128 + lr * 8];
#pragma unroll
    for (int j = 0; j < NJ; ++j) {
      int ncol = wc + (j & 3) * 16 + (j >> 2) * 128;
      short8v bq = *(const short8v*)&stg[(ncol >> 4) * 512 + l * 8];
#pragma unroll
      for (int i = 0; i < 4; ++i)
        acc2[i][j] = __builtin_amdgcn_mfma_f32_16x16x32_bf16(a[i], bq, acc2[i][j], 0, 0, 0);
    }
  }

  // epilogue2: OUT[n'][h] row-major, bias on h
  __hip_bfloat16* Ob = OUT + (size_t)b * N * 128;
#pragma unroll
  for (int i = 0; i < 4; ++i) {
    int h0 = wr + i * 16 + lg * 4;
    float b0 = bias[h0 + 0], b1 = bias[h0 + 1], b2 = bias[h0 + 2], b3 = bias[h0 + 3];
#pragma unroll
    for (int j = 0; j < NJ; ++j) {
      int np = wc + (j & 3) * 16 + (j >> 2) * 128 + lr;
      f32x4 v = acc2[i][j];
      uint2 p;
      p.x = pk2bf(v[0] + b0, v[1] + b1);
      p.y = pk2bf(v[2] + b2, v[3] + b3);
      *(uint2*)(Ob + (size_t)np * 128 + h0) = p;
    }
  }
}

// out[b][h] = mean_c H[b][c][h]; uint4 loads + LDS reduce
__global__ __launch_bounds__(256) void mean_nodes(const __hip_bfloat16* __restrict__ H,
                                                  float* __restrict__ out, int N)
{
  __shared__ float red[16][128];
  int b = blockIdx.x, t = threadIdx.x;
  int rg = t >> 4, ch = t & 15;
  const __hip_bfloat16* Hb = H + (size_t)b * N * 128;
  float s[8] = {};
  for (int c = rg; c < N; c += 16) {
    uint4 u = *(const uint4*)(Hb + (size_t)c * 128 + ch * 8);
    unsigned arr[4] = {u.x, u.y, u.z, u.w};
#pragma unroll
    for (int q = 0; q < 4; ++q) {
      __hip_bfloat162 h2;
      __builtin_memcpy(&h2, &arr[q], 4);
      s[2 * q] += __bfloat162float(h2.x);
      s[2 * q + 1] += __bfloat162float(h2.y);
    }
  }
#pragma unroll
  for (int j = 0; j < 8; ++j) red[rg][ch * 8 + j] = s[j];
  __syncthreads();
  if (t < 128) {
    float tot = 0.f;
#pragma unroll
    for (int g = 0; g < 16; ++g) tot += red[g][t];
    out[b * 128 + t] = tot * (1.0f / N);
  }
}

__global__ void proj_kernel(const float* __restrict__ of, const float* __restrict__ ot,
                            const float* __restrict__ pw, const float* __restrict__ pb,
                            float* __restrict__ out)
{
  int idx = blockIdx.x * 256 + threadIdx.x;  // < 512*64
  int b = idx >> 6, o = idx & 63;
  float s = pb[o];
  const float* f = of + b * 128;
  const float* tt = ot + b * 128;
#pragma unroll 4
  for (int j = 0; j < 128; ++j) s += f[j] * pw[j * 64 + o];
#pragma unroll 4
  for (int j = 0; j < 128; ++j) s += tt[j] * pw[(128 + j) * 64 + o];
  out[idx] = s;
}

extern "C" void kernel_launch(void* const* d_in, const int* in_sizes, int n_in,
                              void* d_out, int out_size, void* d_ws, size_t ws_size,
                              hipStream_t stream)
{
  const float* X_time = (const float*)d_in[0];
  const float* conv_w = (const float*)d_in[1];
  const float* conv_b = (const float*)d_in[2];
  const float* wq_feat = (const float*)d_in[3];
  const float* wk_feat = (const float*)d_in[4];
  const float* wq_time = (const float*)d_in[5];
  const float* wk_time = (const float*)d_in[6];
  const float* gf1_w = (const float*)d_in[7];
  const float* gf1_b = (const float*)d_in[8];
  const float* gf2_w = (const float*)d_in[9];
  const float* gf2_b = (const float*)d_in[10];
  const float* gf3_w = (const float*)d_in[11];
  const float* gf3_b = (const float*)d_in[12];
  const float* gt1_w = (const float*)d_in[13];
  const float* gt1_b = (const float*)d_in[14];
  const float* gt2_w = (const float*)d_in[15];
  const float* gt2_b = (const float*)d_in[16];
  const float* gt3_w = (const float*)d_in[17];
  const float* gt3_b = (const float*)d_in[18];
  const float* proj_w = (const float*)d_in[19];
  const float* proj_b = (const float*)d_in[20];

  typedef __hip_bfloat16 bf16;
  char* ws = (char*)d_ws;
  const size_t MiB = 1ull << 20;
  bf16* XFb = (bf16*)ws;
  bf16* Xtb = (bf16*)(ws + 34 * MiB);
  bf16* Pt = (bf16*)(ws + 68 * MiB);
  bf16* Pf = (bf16*)(ws + 136 * MiB);
  bf16* Xt = (bf16*)(ws + 153 * MiB);
  bf16* F0 = (bf16*)(ws + 68 * MiB);
  bf16* F1 = (bf16*)(ws + 102 * MiB);
  bf16* T0 = (bf16*)ws;
  bf16* T1 = (bf16*)(ws + 34 * MiB);
  char* SM = ws + 187 * MiB;
  float* A_feat = (float*)SM;
  float* A_time = (float*)(SM + 65536);
  float* dis_f = (float*)(SM + 327680);
  float* dis_t = (float*)(SM + 329728);
  bf16* MTf = (bf16*)(SM + 331776);
  bf16* MTt = (bf16*)(SM + 364544);
  bf16* w1f = (bf16*)(SM + 495616);
  bf16* w2f = (bf16*)(SM + 561152);
  bf16* w3f = (bf16*)(SM + 593920);
  bf16* w1t = (bf16*)(SM + 626688);
  bf16* w2t = (bf16*)(SM + 659456);
  bf16* w3t = (bf16*)(SM + 692224);
  bf16* Wcv = (bf16*)(SM + 1249280);
  float* out_f = (float*)(SM + 724992);
  float* out_t = (float*)(SM + 987136);
  float* Pf_part = (float*)(SM + 2 * MiB);
  float* Pt_part = (float*)(SM + 2 * MiB + 524288);

  float* out = (float*)d_out;
  float* outA_f = out + 32768;
  float* outA_t = out + 49152;

  // 1) prep + conv
  prep_x<<<dim3(32, NB), 256, 0, stream>>>(X_time, Xtb, Xt);
  wc_cast<<<192, 256, 0, stream>>>(conv_w, Wcv);
  conv_gemm<<<dim3(2, NB), 256, 0, stream>>>(Xt, Wcv, conv_b, XFb);
  // 2) MFMA grams + per-batch softmax
  gram_mfma<128, 256><<<dim3(2, NB), 256, 0, stream>>>(XFb, wq_feat, wk_feat, Pf, 0.0625f);
  gram_mfma<256, 128><<<dim3(4, NB), 256, 0, stream>>>(Xtb, wq_time, wk_time, Pt,
                                                       0.08838834764831845f);
  // 3) batch mean -> A
  reduceA_part<<<dim3(16, 8), 256, 0, stream>>>(Pf, Pf_part, 16384);
  reduceA_part<<<dim3(64, 8), 256, 0, stream>>>(Pt, Pt_part, 65536);
  reduceA_fin<<<16, 256, 0, stream>>>(Pf_part, A_feat, outA_f, 16384);
  reduceA_fin<<<64, 256, 0, stream>>>(Pt_part, A_time, outA_t, 65536);
  // 4) normalized adjacency + weight transposes
  deg_sum<<<2, 256, 0, stream>>>(A_feat, dis_f, 128);
  deg_sum<<<4, 256, 0, stream>>>(A_time, dis_t, 256);
  mt_bf16<<<64, 256, 0, stream>>>(A_feat, dis_f, MTf, 128);
  mt_bf16<<<256, 256, 0, stream>>>(A_time, dis_t, MTt, 256);
  wt_cast_all<<<448, 256, 0, stream>>>(gf1_w, gf2_w, gf3_w, gt1_w, gt2_w, gt3_w,
                                       w1f, w2f, w3f, w1t, w2t, w3t);

  // 5) feat GCN: 3 fused layers (IN [128][K] -> OUT [128][128])
  gcn_layer<128><<<NB, 256, 0, stream>>>(XFb, 256, w1f, MTf, gf1_b, F0);
  gcn_layer<128><<<NB, 256, 0, stream>>>(F0, 128, w2f, MTf, gf2_b, F1);
  gcn_layer<128><<<NB, 256, 0, stream>>>(F1, 128, w3f, MTf, gf3_b, F0);
  mean_nodes<<<NB, 256, 0, stream>>>(F0, out_f, 128);

  // 6) time GCN: 3 fused layers (IN [256][128] -> OUT [256][128])
  gcn_layer<256><<<NB, 256, 0, stream>>>(Xtb, 128, w1t, MTt, gt1_b, T0);
  gcn_layer<256><<<NB, 256, 0, stream>>>(T0, 128, w2t, MTt, gt2_b, T1);
  gcn_layer<256><<<NB, 256, 0, stream>>>(T1, 128, w3t, MTt, gt3_b, T0);
  mean_nodes<<<NB, 256, 0, stream>>>(T0, out_t, 256);

  // 7) projection
  proj_kernel<<<128, 256, 0, stream>>>(out_f, out_t, proj_w, proj_b, out);
}